// Round 11
// baseline (215.829 us; speedup 1.0000x reference)
//
#include <hip/hip_runtime.h>
#include <hip/hip_bf16.h>

#define Bn 16384
#define Dn 512
#define Hn 1024
#define On 512
#define En 8
#define MTILES 264            // ceil((32768 + 8*127)/128)
#define MAXP (MTILES * 128)   // 33792 padded token-expert pairs
#define NPAIR (Bn * 2)        // 32768
#define SBLK 64               // scan blocks (512 thr each)

typedef __attribute__((ext_vector_type(8))) short bf16x8;
typedef __attribute__((ext_vector_type(4))) float f32x4;

typedef __attribute__((address_space(3))) unsigned lds_u;
typedef __attribute__((address_space(1))) const unsigned glb_u;
// async global->LDS, 16B per lane; LDS dest = wave-uniform base + lane*16
__device__ __forceinline__ void cp16(const unsigned short* g, void* l) {
  __builtin_amdgcn_global_load_lds((glb_u*)g, (lds_u*)l, 16, 0, 0);
}

// bijective XCD-aware remap (T1); valid since our grids are multiples of 8
__device__ __forceinline__ int xcd_swz(int orig, int nwg) {
  int q = nwg >> 3;
  return (orig & 7) * q + (orig >> 3);
}

__device__ __forceinline__ unsigned short f2bf(float f) {
  union { float f; unsigned u; } v; v.f = f;
  unsigned r = v.u + 0x7FFFu + ((v.u >> 16) & 1u);   // RNE
  return (unsigned short)(r >> 16);
}
__device__ __forceinline__ float bf2f(short s) {
  union { unsigned u; float f; } v; v.u = ((unsigned)(unsigned short)s) << 16; return v.f;
}

// ------------- transpose+convert: src [E][R][C] f32 -> dst [E][C][R] bf16 -------------
__global__ __launch_bounds__(256) void k_transpose(const float* __restrict__ s,
                                                   unsigned short* __restrict__ d,
                                                   int R, int C) {
  __shared__ float tile[32][33];
  int ez = blockIdx.z;
  int c0 = blockIdx.x * 32, r0 = blockIdx.y * 32;
  const float* se = s + (size_t)ez * R * C;
  unsigned short* de = d + (size_t)ez * R * C;
  int tx = threadIdx.x, ty = threadIdx.y;
#pragma unroll
  for (int i = 0; i < 32; i += 8)
    tile[ty + i][tx] = se[(size_t)(r0 + ty + i) * C + (c0 + tx)];
  __syncthreads();
#pragma unroll
  for (int i = 0; i < 32; i += 8)
    de[(size_t)(c0 + ty + i) * R + (r0 + tx)] = f2bf(tile[tx][ty + i]);
}

// -------- gate: fp64 dot (exact ordering) + register-only fp32 tail, NO ATOMICS --------
// also converts its x row to bf16 (replaces the separate convert kernel)
__global__ __launch_bounds__(256) void k_gate(const float* __restrict__ x,
    const float* __restrict__ gw, const float* __restrict__ gb,
    unsigned short* __restrict__ xb,
    float* __restrict__ raw_out, float* __restrict__ idx_out,
    int* __restrict__ top_e, float* __restrict__ top_w,
    float* __restrict__ entp) {
  int lane = threadIdx.x & 63, wid = threadIdx.x >> 6;
  int t = blockIdx.x * 4 + wid;
  __shared__ float ent_s[4];
  const float* xr = x + (size_t)t * Dn + lane * 8;
  f32x4 x0 = *(const f32x4*)xr;
  f32x4 x1 = *(const f32x4*)(xr + 4);
  // fused x -> bf16 (16 B per lane, full row per wave)
  ushort4 cv0, cv1;
  cv0.x = f2bf(x0[0]); cv0.y = f2bf(x0[1]); cv0.z = f2bf(x0[2]); cv0.w = f2bf(x0[3]);
  cv1.x = f2bf(x1[0]); cv1.y = f2bf(x1[1]); cv1.z = f2bf(x1[2]); cv1.w = f2bf(x1[3]);
  unsigned short* xbr = xb + (size_t)t * Dn + lane * 8;
  *(ushort4*)xbr = cv0;
  *(ushort4*)(xbr + 4) = cv1;
  double acc[8];
#pragma unroll
  for (int e = 0; e < 8; ++e) acc[e] = 0.0;
#pragma unroll
  for (int j = 0; j < 8; ++j) {
    float xv = (j < 4) ? x0[j] : x1[j - 4];
    const float* wr = gw + (size_t)(lane * 8 + j) * 8;
    f32x4 w0 = *(const f32x4*)wr;
    f32x4 w1 = *(const f32x4*)(wr + 4);
    double xd = (double)xv;
    acc[0] += xd * (double)w0[0]; acc[1] += xd * (double)w0[1];
    acc[2] += xd * (double)w0[2]; acc[3] += xd * (double)w0[3];
    acc[4] += xd * (double)w1[0]; acc[5] += xd * (double)w1[1];
    acc[6] += xd * (double)w1[2]; acc[7] += xd * (double)w1[3];
  }
#pragma unroll
  for (int off = 32; off; off >>= 1)
#pragma unroll
    for (int e = 0; e < 8; ++e) acc[e] += __shfl_xor(acc[e], off, 64);
  double raw[8];
#pragma unroll
  for (int e = 0; e < 8; ++e) raw[e] = acc[e] + (double)gb[e];
  // branchless top-2 (fp64 compares, strict > : ties -> lower index, matches lax.top_k)
  double v0 = raw[0], v1 = -1e300;
  int i0 = 0, i1 = 0;
#pragma unroll
  for (int e = 1; e < 8; ++e) {
    bool g0 = raw[e] > v0;
    bool g1 = raw[e] > v1;
    double nv1 = g0 ? v0 : (g1 ? raw[e] : v1);
    int    ni1 = g0 ? i0 : (g1 ? e      : i1);
    v1 = nv1; i1 = ni1;
    v0 = g0 ? raw[e] : v0;
    i0 = g0 ? e      : i0;
  }
  float pf[8], s = 0.f;
#pragma unroll
  for (int e = 0; e < 8; ++e) { pf[e] = __expf((float)(raw[e] - v0)); s += pf[e]; }
  float inv = 1.f / s, ent = 0.f;
#pragma unroll
  for (int e = 0; e < 8; ++e) { float p = pf[e] * inv; ent -= p * __logf(p + 1e-9f); }
  float p0 = inv;
  float p1 = __expf((float)(v1 - v0)) * inv;
  float cw0 = 1.f / (1.f + __expf(p1 - p0));       // softmax over top-2 PROBS
  if (lane == 0) {
    f32x4 ra, rb;
    ra[0] = (float)raw[0]; ra[1] = (float)raw[1]; ra[2] = (float)raw[2]; ra[3] = (float)raw[3];
    rb[0] = (float)raw[4]; rb[1] = (float)raw[5]; rb[2] = (float)raw[6]; rb[3] = (float)raw[7];
    *(f32x4*)(raw_out + (size_t)t * 8) = ra;
    *(f32x4*)(raw_out + (size_t)t * 8 + 4) = rb;
    idx_out[t * 2 + 0] = (float)i0; idx_out[t * 2 + 1] = (float)i1;
    top_e[t * 2 + 0] = i0; top_e[t * 2 + 1] = i1;
    top_w[t * 2 + 0] = cw0; top_w[t * 2 + 1] = 1.f - cw0;
    ent_s[wid] = ent;
  }
  __syncthreads();
  if (threadIdx.x == 0) entp[blockIdx.x] = (ent_s[0] + ent_s[1]) + (ent_s[2] + ent_s[3]);
}

// ---------- atomic-free routing: ballot histogram -> scan -> ranked scatter ----------
__global__ __launch_bounds__(512) void k_hist(const int* __restrict__ top_e,
                                              int* __restrict__ bc) {
  int p = blockIdx.x * 512 + threadIdx.x;
  int lane = threadIdx.x & 63, w = threadIdx.x >> 6;
  int e = top_e[p];
  __shared__ int wc[8][8];
#pragma unroll
  for (int v = 0; v < 8; ++v) {
    unsigned long long m = __ballot(e == v);
    if (lane == 0) wc[w][v] = __popcll(m);
  }
  __syncthreads();
  if (threadIdx.x < 8) {
    int sum = 0;
#pragma unroll
    for (int w2 = 0; w2 < 8; ++w2) sum += wc[w2][threadIdx.x];
    bc[blockIdx.x * 8 + threadIdx.x] = sum;
  }
}

// 1 block, 512 threads: wave = expert, lane = scan-block; also finalizes entropy
__global__ __launch_bounds__(512) void k_offsets(const int* __restrict__ bc,
    int* __restrict__ ob, int* __restrict__ tile_expert, int* __restrict__ tok,
    const float* __restrict__ entp, float* __restrict__ ent_out) {
  int lane = threadIdx.x & 63;     // scan-block b
  int e = threadIdx.x >> 6;        // expert
  int v = bc[lane * 8 + e];
  int sum = v;
#pragma unroll
  for (int off = 1; off < 64; off <<= 1) {
    int o = __shfl_up(sum, off, 64);
    if (lane >= off) sum += o;
  }
  int excl = sum - v;
  __shared__ int tot8[8], po[9];
  __shared__ float es[512];
  // entropy finalize (independent of the scan)
  float ev = 0.f;
  for (int i = threadIdx.x; i < 4096; i += 512) ev += entp[i];
  es[threadIdx.x] = ev;
  if (lane == 63) tot8[e] = sum;
  __syncthreads();
  for (int o = 256; o; o >>= 1) {
    if (threadIdx.x < o) es[threadIdx.x] += es[threadIdx.x + o];
    __syncthreads();
  }
  if (threadIdx.x == 0) ent_out[0] = es[0] / (float)Bn;
  int seg = 0;
#pragma unroll
  for (int e2 = 0; e2 < 8; ++e2) {
    int padded = ((tot8[e2] + 127) >> 7) << 7;
    seg += (e2 < e) ? padded : 0;
  }
  ob[lane * 8 + e] = seg + excl;
  if (lane == 0) po[e] = seg;
  if (threadIdx.x == 511) po[8] = seg + (((tot8[7] + 127) >> 7) << 7);
  __syncthreads();
  for (int i = threadIdx.x; i < MAXP; i += 512) tok[i] = Bn;  // padding -> zero row of xb
  for (int i = threadIdx.x; i < MTILES; i += 512) {
    int base = i * 128, ee = -1;
#pragma unroll
    for (int j = 0; j < 8; ++j) if (base >= po[j] && base < po[j + 1]) ee = j;
    tile_expert[i] = ee;
  }
}

__global__ __launch_bounds__(512) void k_scatter2(const int* __restrict__ top_e,
    const float* __restrict__ top_w, const int* __restrict__ ob,
    int* __restrict__ tok, float* __restrict__ wgt, int* __restrict__ pos_tk) {
  int p = blockIdx.x * 512 + threadIdx.x;
  int lane = threadIdx.x & 63, w = threadIdx.x >> 6;
  int e = top_e[p];
  __shared__ int wc[8][8];
  unsigned long long lt = (1ULL << lane) - 1;
  int rank = 0;
#pragma unroll
  for (int v = 0; v < 8; ++v) {
    unsigned long long m = __ballot(e == v);
    if (lane == 0) wc[w][v] = __popcll(m);
    if (e == v) rank = __popcll(m & lt);
  }
  __syncthreads();
  int wpre = 0;
#pragma unroll
  for (int w2 = 0; w2 < 8; ++w2) wpre += (w2 < w) ? wc[w2][e] : 0;   // LDS runtime idx ok
  int pos = ob[blockIdx.x * 8 + e] + wpre + rank;
  tok[pos] = p >> 1;
  wgt[pos] = top_w[p];
  pos_tk[p] = pos;
}

// ============ GEMM1: h[pair][H] = relu(x[tok]·w1[e] + b1[e]), 128x256 tile ============
// Single-buffer 2-barrier K-loop (R9-proven) with widened N: 8 waves (2m x 4n),
// per-wave 64x64 (acc[4][4], no spill). A staged once per 256 output cols.
__global__ __launch_bounds__(512) void k_gemm1(const unsigned short* __restrict__ xb,
    const unsigned short* __restrict__ w1t, const float* __restrict__ b1,
    const int* __restrict__ tok, const int* __restrict__ tile_expert,
    unsigned short* __restrict__ h) {
  const int wg = xcd_swz(blockIdx.x, MTILES * (Hn / 256));
  const int mt = wg >> 2, nb = wg & 3;
  int e = tile_expert[mt];
  if (e < 0) return;
  const int m0 = mt * 128, n0 = nb * 256;
  __shared__ char As[16384];     // [128][64] bf16, swizzled
  __shared__ char Bs[32768];     // [256][64] bf16, swizzled
  const int tid = threadIdx.x, lane = tid & 63, wv = tid >> 6;
  const int wm = wv >> 2, wn = wv & 3;
  const int rA = tid >> 3;                              // 0..63
  const int c8 = ((tid & 7) ^ ((tid >> 3) & 7)) * 8;    // pre-swizzled k-chunk (elements)
  int trow[2];
#pragma unroll
  for (int i = 0; i < 2; ++i) trow[i] = tok[m0 + i * 64 + rA];
  const unsigned short* w1e = w1t + (size_t)e * Hn * Dn;
  f32x4 acc[4][4];
#pragma unroll
  for (int m = 0; m < 4; ++m)
#pragma unroll
    for (int n = 0; n < 4; ++n) acc[m][n] = (f32x4){0.f, 0.f, 0.f, 0.f};

  for (int kt = 0; kt < Dn / 64; ++kt) {
    const int k0 = kt * 64;
    if (kt) __syncthreads();
#pragma unroll
    for (int i = 0; i < 2; ++i)
      cp16(xb + (size_t)trow[i] * Dn + k0 + c8, As + i * 8192 + wv * 1024);
#pragma unroll
    for (int i = 0; i < 4; ++i)
      cp16(w1e + (size_t)(n0 + i * 64 + rA) * Dn + k0 + c8, Bs + i * 8192 + wv * 1024);
    __syncthreads();
#pragma unroll
    for (int kk = 0; kk < 2; ++kk) {
      const int bc = kk * 64 + (lane >> 4) * 16;
      bf16x8 a[4], b[4];
#pragma unroll
      for (int m = 0; m < 4; ++m) {
        int r = wm * 64 + m * 16 + (lane & 15);
        a[m] = *(const bf16x8*)(As + r * 128 + (bc ^ ((r & 7) << 4)));
      }
#pragma unroll
      for (int n = 0; n < 4; ++n) {
        int r = wn * 64 + n * 16 + (lane & 15);
        b[n] = *(const bf16x8*)(Bs + r * 128 + (bc ^ ((r & 7) << 4)));
      }
#pragma unroll
      for (int m = 0; m < 4; ++m)
#pragma unroll
        for (int n = 0; n < 4; ++n)
          acc[m][n] = __builtin_amdgcn_mfma_f32_16x16x32_bf16(a[m], b[n], acc[m][n], 0, 0, 0);
    }
  }
#pragma unroll
  for (int n = 0; n < 4; ++n) {
    int gcol = n0 + wn * 64 + n * 16 + (lane & 15);
    float bias = b1[e * Hn + gcol];
#pragma unroll
    for (int m = 0; m < 4; ++m) {
      int grow = m0 + wm * 64 + m * 16 + ((lane >> 4) << 2);
#pragma unroll
      for (int r = 0; r < 4; ++r) {
        float v = fmaxf(acc[m][n][r] + bias, 0.f);
        h[(size_t)(grow + r) * Hn + gcol] = f2bf(v);
      }
    }
  }
}

// ============ GEMM2: y[pair][O] = h·w2[e] + b2[e] (bf16), 128x256 tile ============
__global__ __launch_bounds__(512) void k_gemm2(const unsigned short* __restrict__ h,
    const unsigned short* __restrict__ w2t, const float* __restrict__ b2,
    const int* __restrict__ tile_expert, unsigned short* __restrict__ y) {
  const int wg = xcd_swz(blockIdx.x, MTILES * (On / 256));
  const int mt = wg >> 1, nb = wg & 1;
  int e = tile_expert[mt];
  if (e < 0) return;
  const int m0 = mt * 128, n0 = nb * 256;
  __shared__ char As[16384];
  __shared__ char Bs[32768];
  const int tid = threadIdx.x, lane = tid & 63, wv = tid >> 6;
  const int wm = wv >> 2, wn = wv & 3;
  const int rA = tid >> 3;
  const int c8 = ((tid & 7) ^ ((tid >> 3) & 7)) * 8;
  const unsigned short* w2e = w2t + (size_t)e * On * Hn;
  f32x4 acc[4][4];
#pragma unroll
  for (int m = 0; m < 4; ++m)
#pragma unroll
    for (int n = 0; n < 4; ++n) acc[m][n] = (f32x4){0.f, 0.f, 0.f, 0.f};

  for (int kt = 0; kt < Hn / 64; ++kt) {
    const int k0 = kt * 64;
    if (kt) __syncthreads();
#pragma unroll
    for (int i = 0; i < 2; ++i)
      cp16(h + (size_t)(m0 + i * 64 + rA) * Hn + k0 + c8, As + i * 8192 + wv * 1024);
#pragma unroll
    for (int i = 0; i < 4; ++i)
      cp16(w2e + (size_t)(n0 + i * 64 + rA) * Hn + k0 + c8, Bs + i * 8192 + wv * 1024);
    __syncthreads();
#pragma unroll
    for (int kk = 0; kk < 2; ++kk) {
      const int bc = kk * 64 + (lane >> 4) * 16;
      bf16x8 a[4], b[4];
#pragma unroll
      for (int m = 0; m < 4; ++m) {
        int r = wm * 64 + m * 16 + (lane & 15);
        a[m] = *(const bf16x8*)(As + r * 128 + (bc ^ ((r & 7) << 4)));
      }
#pragma unroll
      for (int n = 0; n < 4; ++n) {
        int r = wn * 64 + n * 16 + (lane & 15);
        b[n] = *(const bf16x8*)(Bs + r * 128 + (bc ^ ((r & 7) << 4)));
      }
#pragma unroll
      for (int m = 0; m < 4; ++m)
#pragma unroll
        for (int n = 0; n < 4; ++n)
          acc[m][n] = __builtin_amdgcn_mfma_f32_16x16x32_bf16(a[m], b[n], acc[m][n], 0, 0, 0);
    }
  }
#pragma unroll
  for (int n = 0; n < 4; ++n) {
    int gcol = n0 + wn * 64 + n * 16 + (lane & 15);
    float bias = b2[e * On + gcol];
#pragma unroll
    for (int m = 0; m < 4; ++m) {
      int grow = m0 + wm * 64 + m * 16 + ((lane >> 4) << 2);
#pragma unroll
      for (int r = 0; r < 4; ++r)
        y[(size_t)(grow + r) * On + gcol] = f2bf(acc[m][n][r] + bias);
    }
  }
}

// ---------------- combine: out[t] = w0*y[p0] + w1*y[p1] ----------------
__global__ __launch_bounds__(256) void k_combine(const unsigned short* __restrict__ y,
    const int* __restrict__ pos_tk, const float* __restrict__ top_w,
    float* __restrict__ out) {
  int wid = threadIdx.x >> 6, lane = threadIdx.x & 63;
  int t = blockIdx.x * 4 + wid;
  int p0 = pos_tk[t * 2], p1 = pos_tk[t * 2 + 1];
  float w0 = top_w[t * 2], w1 = top_w[t * 2 + 1];
  bf16x8 a = *(const bf16x8*)(y + (size_t)p0 * On + lane * 8);
  bf16x8 b = *(const bf16x8*)(y + (size_t)p1 * On + lane * 8);
  f32x4 o0, o1;
#pragma unroll
  for (int j = 0; j < 4; ++j) {
    o0[j] = w0 * bf2f(a[j]) + w1 * bf2f(b[j]);
    o1[j] = w0 * bf2f(a[j + 4]) + w1 * bf2f(b[j + 4]);
  }
  float* op = out + (size_t)t * On + lane * 8;
  *(f32x4*)op = o0;
  *(f32x4*)(op + 4) = o1;
}

extern "C" void kernel_launch(void* const* d_in, const int* in_sizes, int n_in,
                              void* d_out, int out_size, void* d_ws, size_t ws_size,
                              hipStream_t stream) {
  const float* x  = (const float*)d_in[0];
  const float* gw = (const float*)d_in[1];
  const float* gb = (const float*)d_in[2];
  const float* w1 = (const float*)d_in[3];
  const float* b1 = (const float*)d_in[4];
  const float* w2 = (const float*)d_in[5];
  const float* b2 = (const float*)d_in[6];
  float* out     = (float*)d_out;
  float* raw_out = out + (size_t)Bn * On;
  float* idx_out = raw_out + (size_t)Bn * En;
  float* ent_out = idx_out + (size_t)Bn * 2;

  char* ws = (char*)d_ws;
  size_t off = 0;
  auto alloc = [&](size_t bytes) { char* p = ws + off; off += (bytes + 255) & ~(size_t)255; return p; };
  unsigned short* xb   = (unsigned short*)alloc((size_t)(Bn + 1) * Dn * 2);  // +1 zero row
  unsigned short* w1t  = (unsigned short*)alloc((size_t)En * Hn * Dn * 2);
  unsigned short* w2t  = (unsigned short*)alloc((size_t)En * On * Hn * 2);
  unsigned short* hbuf = (unsigned short*)alloc((size_t)MAXP * Hn * 2);
  unsigned short* ybuf = (unsigned short*)alloc((size_t)MAXP * On * 2);
  int*   tok    = (int*)alloc((size_t)MAXP * 4);
  float* wgt    = (float*)alloc((size_t)MAXP * 4);
  int*   pos_tk = (int*)alloc((size_t)NPAIR * 4);
  int*   top_e  = (int*)alloc((size_t)NPAIR * 4);
  float* top_w  = (float*)alloc((size_t)NPAIR * 4);
  int*   bc     = (int*)alloc(SBLK * 8 * 4);
  int*   ob     = (int*)alloc(SBLK * 8 * 4);
  int*   tile_expert = (int*)alloc(MTILES * 4);
  float* entp   = (float*)alloc(4096 * 4);

  hipMemsetAsync(xb + (size_t)Bn * Dn, 0, Dn * 2, stream);   // zero row for padding

  k_transpose<<<dim3(Hn / 32, Dn / 32, En), dim3(32, 8), 0, stream>>>(w1, w1t, Dn, Hn);
  k_transpose<<<dim3(On / 32, Hn / 32, En), dim3(32, 8), 0, stream>>>(w2, w2t, Hn, On);
  k_gate<<<Bn / 4, 256, 0, stream>>>(x, gw, gb, xb, raw_out, idx_out, top_e, top_w, entp);
  k_hist<<<SBLK, 512, 0, stream>>>(top_e, bc);
  k_offsets<<<1, 512, 0, stream>>>(bc, ob, tile_expert, tok, entp, ent_out);
  k_scatter2<<<SBLK, 512, 0, stream>>>(top_e, top_w, ob, tok, wgt, pos_tk);
  k_gemm1<<<MTILES * (Hn / 256), 512, 0, stream>>>(xb, w1t, b1, tok, tile_expert, hbuf);
  k_gemm2<<<MTILES * (On / 256), 512, 0, stream>>>(hbuf, w2t, b2, tile_expert, ybuf);
  k_combine<<<Bn / 4, 256, 0, stream>>>(ybuf, pos_tk, top_w, out);
}

// Round 12
// 163.516 us; speedup vs baseline: 1.3199x; 1.3199x over previous
//
#include <hip/hip_runtime.h>
#include <hip/hip_bf16.h>

#define Bn 16384
#define Dn 512
#define Hn 1024
#define On 512
#define En 8
#define MTILES 264            // ceil((32768 + 8*127)/128)
#define MAXP (MTILES * 128)   // 33792 padded token-expert pairs
#define NPAIR (Bn * 2)        // 32768
#define SBLK 64               // scan blocks (512 thr each)

typedef __attribute__((ext_vector_type(8))) short bf16x8;
typedef __attribute__((ext_vector_type(4))) float f32x4;

typedef __attribute__((address_space(3))) unsigned lds_u;
typedef __attribute__((address_space(1))) const unsigned glb_u;
// async global->LDS, 16B per lane; LDS dest = wave-uniform base + lane*16
__device__ __forceinline__ void cp16(const unsigned short* g, void* l) {
  __builtin_amdgcn_global_load_lds((glb_u*)g, (lds_u*)l, 16, 0, 0);
}

// bijective XCD-aware remap (T1); valid since our grids are multiples of 8
__device__ __forceinline__ int xcd_swz(int orig, int nwg) {
  int q = nwg >> 3;
  return (orig & 7) * q + (orig >> 3);
}

__device__ __forceinline__ unsigned short f2bf(float f) {
  union { float f; unsigned u; } v; v.f = f;
  unsigned r = v.u + 0x7FFFu + ((v.u >> 16) & 1u);   // RNE
  return (unsigned short)(r >> 16);
}
__device__ __forceinline__ float bf2f(short s) {
  union { unsigned u; float f; } v; v.u = ((unsigned)(unsigned short)s) << 16; return v.f;
}

// ------- fused transpose+convert for BOTH weights in one launch -------
// bid < 4096: w1 [Dn][Hn] -> w1t [Hn][Dn];  else: w2 [Hn][On] -> w2t [On][Hn]
__global__ __launch_bounds__(256) void k_transpose2(const float* __restrict__ w1,
    const float* __restrict__ w2, unsigned short* __restrict__ w1t,
    unsigned short* __restrict__ w2t) {
  __shared__ float tile[32][33];
  int bid = blockIdx.x;
  const float* s; unsigned short* d; int R, C, c0, r0, ez;
  if (bid < 4096) {
    ez = bid >> 9; int tl = bid & 511;
    R = Dn; C = Hn; c0 = (tl & 31) * 32; r0 = (tl >> 5) * 32;
    s = w1; d = w1t;
  } else {
    ez = (bid - 4096) >> 9; int tl = bid & 511;
    R = Hn; C = On; c0 = (tl & 15) * 32; r0 = (tl >> 4) * 32;
    s = w2; d = w2t;
  }
  const float* se = s + (size_t)ez * R * C;
  unsigned short* de = d + (size_t)ez * R * C;
  int tx = threadIdx.x, ty = threadIdx.y;
#pragma unroll
  for (int i = 0; i < 32; i += 8)
    tile[ty + i][tx] = se[(size_t)(r0 + ty + i) * C + (c0 + tx)];
  __syncthreads();
#pragma unroll
  for (int i = 0; i < 32; i += 8)
    de[(size_t)(c0 + ty + i) * R + (r0 + tx)] = f2bf(tile[tx][ty + i]);
}

// -------- gate: fp64 dot (exact ordering) + register-only fp32 tail, NO ATOMICS --------
// also converts its x row to bf16 (replaces the separate convert kernel)
__global__ __launch_bounds__(256) void k_gate(const float* __restrict__ x,
    const float* __restrict__ gw, const float* __restrict__ gb,
    unsigned short* __restrict__ xb,
    float* __restrict__ raw_out, float* __restrict__ idx_out,
    int* __restrict__ top_e, float* __restrict__ top_w,
    float* __restrict__ entp) {
  int lane = threadIdx.x & 63, wid = threadIdx.x >> 6;
  int t = blockIdx.x * 4 + wid;
  __shared__ float ent_s[4];
  const float* xr = x + (size_t)t * Dn + lane * 8;
  f32x4 x0 = *(const f32x4*)xr;
  f32x4 x1 = *(const f32x4*)(xr + 4);
  // fused x -> bf16 (16 B per lane, full row per wave)
  ushort4 cv0, cv1;
  cv0.x = f2bf(x0[0]); cv0.y = f2bf(x0[1]); cv0.z = f2bf(x0[2]); cv0.w = f2bf(x0[3]);
  cv1.x = f2bf(x1[0]); cv1.y = f2bf(x1[1]); cv1.z = f2bf(x1[2]); cv1.w = f2bf(x1[3]);
  unsigned short* xbr = xb + (size_t)t * Dn + lane * 8;
  *(ushort4*)xbr = cv0;
  *(ushort4*)(xbr + 4) = cv1;
  double acc[8];
#pragma unroll
  for (int e = 0; e < 8; ++e) acc[e] = 0.0;
#pragma unroll
  for (int j = 0; j < 8; ++j) {
    float xv = (j < 4) ? x0[j] : x1[j - 4];
    const float* wr = gw + (size_t)(lane * 8 + j) * 8;
    f32x4 w0 = *(const f32x4*)wr;
    f32x4 w1 = *(const f32x4*)(wr + 4);
    double xd = (double)xv;
    acc[0] += xd * (double)w0[0]; acc[1] += xd * (double)w0[1];
    acc[2] += xd * (double)w0[2]; acc[3] += xd * (double)w0[3];
    acc[4] += xd * (double)w1[0]; acc[5] += xd * (double)w1[1];
    acc[6] += xd * (double)w1[2]; acc[7] += xd * (double)w1[3];
  }
#pragma unroll
  for (int off = 32; off; off >>= 1)
#pragma unroll
    for (int e = 0; e < 8; ++e) acc[e] += __shfl_xor(acc[e], off, 64);
  double raw[8];
#pragma unroll
  for (int e = 0; e < 8; ++e) raw[e] = acc[e] + (double)gb[e];
  // branchless top-2 (fp64 compares, strict > : ties -> lower index, matches lax.top_k)
  double v0 = raw[0], v1 = -1e300;
  int i0 = 0, i1 = 0;
#pragma unroll
  for (int e = 1; e < 8; ++e) {
    bool g0 = raw[e] > v0;
    bool g1 = raw[e] > v1;
    double nv1 = g0 ? v0 : (g1 ? raw[e] : v1);
    int    ni1 = g0 ? i0 : (g1 ? e      : i1);
    v1 = nv1; i1 = ni1;
    v0 = g0 ? raw[e] : v0;
    i0 = g0 ? e      : i0;
  }
  float pf[8], s = 0.f;
#pragma unroll
  for (int e = 0; e < 8; ++e) { pf[e] = __expf((float)(raw[e] - v0)); s += pf[e]; }
  float inv = 1.f / s, ent = 0.f;
#pragma unroll
  for (int e = 0; e < 8; ++e) { float p = pf[e] * inv; ent -= p * __logf(p + 1e-9f); }
  float p0 = inv;
  float p1 = __expf((float)(v1 - v0)) * inv;
  float cw0 = 1.f / (1.f + __expf(p1 - p0));       // softmax over top-2 PROBS
  if (lane == 0) {
    f32x4 ra, rb;
    ra[0] = (float)raw[0]; ra[1] = (float)raw[1]; ra[2] = (float)raw[2]; ra[3] = (float)raw[3];
    rb[0] = (float)raw[4]; rb[1] = (float)raw[5]; rb[2] = (float)raw[6]; rb[3] = (float)raw[7];
    *(f32x4*)(raw_out + (size_t)t * 8) = ra;
    *(f32x4*)(raw_out + (size_t)t * 8 + 4) = rb;
    idx_out[t * 2 + 0] = (float)i0; idx_out[t * 2 + 1] = (float)i1;
    top_e[t * 2 + 0] = i0; top_e[t * 2 + 1] = i1;
    top_w[t * 2 + 0] = cw0; top_w[t * 2 + 1] = 1.f - cw0;
    ent_s[wid] = ent;
  }
  __syncthreads();
  if (threadIdx.x == 0) entp[blockIdx.x] = (ent_s[0] + ent_s[1]) + (ent_s[2] + ent_s[3]);
}

// ---------- atomic-free routing: ballot histogram -> scan -> ranked scatter ----------
__global__ __launch_bounds__(512) void k_hist(const int* __restrict__ top_e,
                                              int* __restrict__ bc) {
  int p = blockIdx.x * 512 + threadIdx.x;
  int lane = threadIdx.x & 63, w = threadIdx.x >> 6;
  int e = top_e[p];
  __shared__ int wc[8][8];
#pragma unroll
  for (int v = 0; v < 8; ++v) {
    unsigned long long m = __ballot(e == v);
    if (lane == 0) wc[w][v] = __popcll(m);
  }
  __syncthreads();
  if (threadIdx.x < 8) {
    int sum = 0;
#pragma unroll
    for (int w2 = 0; w2 < 8; ++w2) sum += wc[w2][threadIdx.x];
    bc[blockIdx.x * 8 + threadIdx.x] = sum;
  }
}

// 1 block, 512 threads: wave = expert, lane = scan-block; also finalizes entropy
__global__ __launch_bounds__(512) void k_offsets(const int* __restrict__ bc,
    int* __restrict__ ob, int* __restrict__ tile_expert, int* __restrict__ tok,
    const float* __restrict__ entp, float* __restrict__ ent_out) {
  int lane = threadIdx.x & 63;     // scan-block b
  int e = threadIdx.x >> 6;        // expert
  int v = bc[lane * 8 + e];
  int sum = v;
#pragma unroll
  for (int off = 1; off < 64; off <<= 1) {
    int o = __shfl_up(sum, off, 64);
    if (lane >= off) sum += o;
  }
  int excl = sum - v;
  __shared__ int tot8[8], po[9];
  __shared__ float es[512];
  // entropy finalize (independent of the scan)
  float ev = 0.f;
  for (int i = threadIdx.x; i < 4096; i += 512) ev += entp[i];
  es[threadIdx.x] = ev;
  if (lane == 63) tot8[e] = sum;
  __syncthreads();
  for (int o = 256; o; o >>= 1) {
    if (threadIdx.x < o) es[threadIdx.x] += es[threadIdx.x + o];
    __syncthreads();
  }
  if (threadIdx.x == 0) ent_out[0] = es[0] / (float)Bn;
  int seg = 0;
#pragma unroll
  for (int e2 = 0; e2 < 8; ++e2) {
    int padded = ((tot8[e2] + 127) >> 7) << 7;
    seg += (e2 < e) ? padded : 0;
  }
  ob[lane * 8 + e] = seg + excl;
  if (lane == 0) po[e] = seg;
  if (threadIdx.x == 511) po[8] = seg + (((tot8[7] + 127) >> 7) << 7);
  __syncthreads();
  for (int i = threadIdx.x; i < MAXP; i += 512) tok[i] = Bn;  // padding -> zero row of xb
  for (int i = threadIdx.x; i < MTILES; i += 512) {
    int base = i * 128, ee = -1;
#pragma unroll
    for (int j = 0; j < 8; ++j) if (base >= po[j] && base < po[j + 1]) ee = j;
    tile_expert[i] = ee;
  }
}

__global__ __launch_bounds__(512) void k_scatter2(const int* __restrict__ top_e,
    const float* __restrict__ top_w, const int* __restrict__ ob,
    int* __restrict__ tok, float* __restrict__ wgt, int* __restrict__ pos_tk) {
  int p = blockIdx.x * 512 + threadIdx.x;
  int lane = threadIdx.x & 63, w = threadIdx.x >> 6;
  int e = top_e[p];
  __shared__ int wc[8][8];
  unsigned long long lt = (1ULL << lane) - 1;
  int rank = 0;
#pragma unroll
  for (int v = 0; v < 8; ++v) {
    unsigned long long m = __ballot(e == v);
    if (lane == 0) wc[w][v] = __popcll(m);
    if (e == v) rank = __popcll(m & lt);
  }
  __syncthreads();
  int wpre = 0;
#pragma unroll
  for (int w2 = 0; w2 < 8; ++w2) wpre += (w2 < w) ? wc[w2][e] : 0;   // LDS runtime idx ok
  int pos = ob[blockIdx.x * 8 + e] + wpre + rank;
  tok[pos] = p >> 1;
  wgt[pos] = top_w[p];
  pos_tk[p] = pos;
}

// ============ GEMM1: h[pair][H] = relu(x[tok]·w1[e] + b1[e]), 128x128 tile ============
// R9-proven: single-buffer 2-barrier K-loop, 4 waves, XCD swizzle, global_load_lds(16B)
__global__ __launch_bounds__(256) void k_gemm1(const unsigned short* __restrict__ xb,
    const unsigned short* __restrict__ w1t, const float* __restrict__ b1,
    const int* __restrict__ tok, const int* __restrict__ tile_expert,
    unsigned short* __restrict__ h) {
  const int wg = xcd_swz(blockIdx.x, MTILES * (Hn / 128));
  const int mt = wg >> 3, nb = wg & 7;
  int e = tile_expert[mt];
  if (e < 0) return;
  const int m0 = mt * 128, n0 = nb * 128;
  __shared__ char As[16384];
  __shared__ char Bs[16384];
  const int tid = threadIdx.x, lane = tid & 63, wv = tid >> 6;
  const int wm = wv >> 1, wn = wv & 1;
  const int rA = tid >> 3;
  const int c8 = ((tid & 7) ^ ((tid >> 3) & 7)) * 8;
  int trow[4];
#pragma unroll
  for (int i = 0; i < 4; ++i) trow[i] = tok[m0 + i * 32 + rA];
  const unsigned short* w1e = w1t + (size_t)e * Hn * Dn;
  f32x4 acc[4][4];
#pragma unroll
  for (int m = 0; m < 4; ++m)
#pragma unroll
    for (int n = 0; n < 4; ++n) acc[m][n] = (f32x4){0.f, 0.f, 0.f, 0.f};

  for (int kt = 0; kt < Dn / 64; ++kt) {
    const int k0 = kt * 64;
    if (kt) __syncthreads();
#pragma unroll
    for (int i = 0; i < 4; ++i)
      cp16(xb + (size_t)trow[i] * Dn + k0 + c8, As + i * 4096 + wv * 1024);
#pragma unroll
    for (int i = 0; i < 4; ++i)
      cp16(w1e + (size_t)(n0 + i * 32 + rA) * Dn + k0 + c8, Bs + i * 4096 + wv * 1024);
    __syncthreads();
#pragma unroll
    for (int kk = 0; kk < 2; ++kk) {
      const int bc = kk * 64 + (lane >> 4) * 16;
      bf16x8 a[4], b[4];
#pragma unroll
      for (int m = 0; m < 4; ++m) {
        int r = wm * 64 + m * 16 + (lane & 15);
        a[m] = *(const bf16x8*)(As + r * 128 + (bc ^ ((r & 7) << 4)));
      }
#pragma unroll
      for (int n = 0; n < 4; ++n) {
        int r = wn * 64 + n * 16 + (lane & 15);
        b[n] = *(const bf16x8*)(Bs + r * 128 + (bc ^ ((r & 7) << 4)));
      }
#pragma unroll
      for (int m = 0; m < 4; ++m)
#pragma unroll
        for (int n = 0; n < 4; ++n)
          acc[m][n] = __builtin_amdgcn_mfma_f32_16x16x32_bf16(a[m], b[n], acc[m][n], 0, 0, 0);
    }
  }
#pragma unroll
  for (int n = 0; n < 4; ++n) {
    int gcol = n0 + wn * 64 + n * 16 + (lane & 15);
    float bias = b1[e * Hn + gcol];
#pragma unroll
    for (int m = 0; m < 4; ++m) {
      int grow = m0 + wm * 64 + m * 16 + ((lane >> 4) << 2);
#pragma unroll
      for (int r = 0; r < 4; ++r) {
        float v = fmaxf(acc[m][n][r] + bias, 0.f);
        h[(size_t)(grow + r) * Hn + gcol] = f2bf(v);
      }
    }
  }
}

// ============ GEMM2: y[pair][O] = h·w2[e] + b2[e] (bf16), 128x128 tile ============
__global__ __launch_bounds__(256) void k_gemm2(const unsigned short* __restrict__ h,
    const unsigned short* __restrict__ w2t, const float* __restrict__ b2,
    const int* __restrict__ tile_expert, unsigned short* __restrict__ y) {
  const int wg = xcd_swz(blockIdx.x, MTILES * (On / 128));
  const int mt = wg >> 2, nb = wg & 3;
  int e = tile_expert[mt];
  if (e < 0) return;
  const int m0 = mt * 128, n0 = nb * 128;
  __shared__ char As[16384];
  __shared__ char Bs[16384];
  const int tid = threadIdx.x, lane = tid & 63, wv = tid >> 6;
  const int wm = wv >> 1, wn = wv & 1;
  const int rA = tid >> 3;
  const int c8 = ((tid & 7) ^ ((tid >> 3) & 7)) * 8;
  const unsigned short* w2e = w2t + (size_t)e * On * Hn;
  f32x4 acc[4][4];
#pragma unroll
  for (int m = 0; m < 4; ++m)
#pragma unroll
    for (int n = 0; n < 4; ++n) acc[m][n] = (f32x4){0.f, 0.f, 0.f, 0.f};

  for (int kt = 0; kt < Hn / 64; ++kt) {
    const int k0 = kt * 64;
    if (kt) __syncthreads();
#pragma unroll
    for (int i = 0; i < 4; ++i)
      cp16(h + (size_t)(m0 + i * 32 + rA) * Hn + k0 + c8, As + i * 4096 + wv * 1024);
#pragma unroll
    for (int i = 0; i < 4; ++i)
      cp16(w2e + (size_t)(n0 + i * 32 + rA) * Hn + k0 + c8, Bs + i * 4096 + wv * 1024);
    __syncthreads();
#pragma unroll
    for (int kk = 0; kk < 2; ++kk) {
      const int bc = kk * 64 + (lane >> 4) * 16;
      bf16x8 a[4], b[4];
#pragma unroll
      for (int m = 0; m < 4; ++m) {
        int r = wm * 64 + m * 16 + (lane & 15);
        a[m] = *(const bf16x8*)(As + r * 128 + (bc ^ ((r & 7) << 4)));
      }
#pragma unroll
      for (int n = 0; n < 4; ++n) {
        int r = wn * 64 + n * 16 + (lane & 15);
        b[n] = *(const bf16x8*)(Bs + r * 128 + (bc ^ ((r & 7) << 4)));
      }
#pragma unroll
      for (int m = 0; m < 4; ++m)
#pragma unroll
        for (int n = 0; n < 4; ++n)
          acc[m][n] = __builtin_amdgcn_mfma_f32_16x16x32_bf16(a[m], b[n], acc[m][n], 0, 0, 0);
    }
  }
#pragma unroll
  for (int n = 0; n < 4; ++n) {
    int gcol = n0 + wn * 64 + n * 16 + (lane & 15);
    float bias = b2[e * On + gcol];
#pragma unroll
    for (int m = 0; m < 4; ++m) {
      int grow = m0 + wm * 64 + m * 16 + ((lane >> 4) << 2);
#pragma unroll
      for (int r = 0; r < 4; ++r)
        y[(size_t)(grow + r) * On + gcol] = f2bf(acc[m][n][r] + bias);
    }
  }
}

// ---------------- combine: out[t] = w0*y[p0] + w1*y[p1] ----------------
__global__ __launch_bounds__(256) void k_combine(const unsigned short* __restrict__ y,
    const int* __restrict__ pos_tk, const float* __restrict__ top_w,
    float* __restrict__ out) {
  int wid = threadIdx.x >> 6, lane = threadIdx.x & 63;
  int t = blockIdx.x * 4 + wid;
  int p0 = pos_tk[t * 2], p1 = pos_tk[t * 2 + 1];
  float w0 = top_w[t * 2], w1 = top_w[t * 2 + 1];
  bf16x8 a = *(const bf16x8*)(y + (size_t)p0 * On + lane * 8);
  bf16x8 b = *(const bf16x8*)(y + (size_t)p1 * On + lane * 8);
  f32x4 o0, o1;
#pragma unroll
  for (int j = 0; j < 4; ++j) {
    o0[j] = w0 * bf2f(a[j]) + w1 * bf2f(b[j]);
    o1[j] = w0 * bf2f(a[j + 4]) + w1 * bf2f(b[j + 4]);
  }
  float* op = out + (size_t)t * On + lane * 8;
  *(f32x4*)op = o0;
  *(f32x4*)(op + 4) = o1;
}

extern "C" void kernel_launch(void* const* d_in, const int* in_sizes, int n_in,
                              void* d_out, int out_size, void* d_ws, size_t ws_size,
                              hipStream_t stream) {
  const float* x  = (const float*)d_in[0];
  const float* gw = (const float*)d_in[1];
  const float* gb = (const float*)d_in[2];
  const float* w1 = (const float*)d_in[3];
  const float* b1 = (const float*)d_in[4];
  const float* w2 = (const float*)d_in[5];
  const float* b2 = (const float*)d_in[6];
  float* out     = (float*)d_out;
  float* raw_out = out + (size_t)Bn * On;
  float* idx_out = raw_out + (size_t)Bn * En;
  float* ent_out = idx_out + (size_t)Bn * 2;

  char* ws = (char*)d_ws;
  size_t off = 0;
  auto alloc = [&](size_t bytes) { char* p = ws + off; off += (bytes + 255) & ~(size_t)255; return p; };
  unsigned short* xb   = (unsigned short*)alloc((size_t)(Bn + 1) * Dn * 2);  // +1 zero row
  unsigned short* w1t  = (unsigned short*)alloc((size_t)En * Hn * Dn * 2);
  unsigned short* w2t  = (unsigned short*)alloc((size_t)En * On * Hn * 2);
  unsigned short* hbuf = (unsigned short*)alloc((size_t)MAXP * Hn * 2);
  unsigned short* ybuf = (unsigned short*)alloc((size_t)MAXP * On * 2);
  int*   tok    = (int*)alloc((size_t)MAXP * 4);
  float* wgt    = (float*)alloc((size_t)MAXP * 4);
  int*   pos_tk = (int*)alloc((size_t)NPAIR * 4);
  int*   top_e  = (int*)alloc((size_t)NPAIR * 4);
  float* top_w  = (float*)alloc((size_t)NPAIR * 4);
  int*   bc     = (int*)alloc(SBLK * 8 * 4);
  int*   ob     = (int*)alloc(SBLK * 8 * 4);
  int*   tile_expert = (int*)alloc(MTILES * 4);
  float* entp   = (float*)alloc(4096 * 4);

  hipMemsetAsync(xb + (size_t)Bn * Dn, 0, Dn * 2, stream);   // zero row for padding

  k_transpose2<<<8192, dim3(32, 8), 0, stream>>>(w1, w2, w1t, w2t);
  k_gate<<<Bn / 4, 256, 0, stream>>>(x, gw, gb, xb, raw_out, idx_out, top_e, top_w, entp);
  k_hist<<<SBLK, 512, 0, stream>>>(top_e, bc);
  k_offsets<<<1, 512, 0, stream>>>(bc, ob, tile_expert, tok, entp, ent_out);
  k_scatter2<<<SBLK, 512, 0, stream>>>(top_e, top_w, ob, tok, wgt, pos_tk);
  k_gemm1<<<MTILES * (Hn / 128), 256, 0, stream>>>(xb, w1t, b1, tok, tile_expert, hbuf);
  k_gemm2<<<MTILES * (On / 128), 256, 0, stream>>>(hbuf, w2t, b2, tile_expert, ybuf);
  k_combine<<<Bn / 4, 256, 0, stream>>>(ybuf, pos_tk, top_w, out);
}

// Round 14
// 161.064 us; speedup vs baseline: 1.3400x; 1.0152x over previous
//
#include <hip/hip_runtime.h>
#include <hip/hip_bf16.h>

#define Bn 16384
#define Dn 512
#define Hn 1024
#define On 512
#define En 8
#define MTILES 264            // ceil((32768 + 8*127)/128)
#define MAXP (MTILES * 128)   // 33792 padded token-expert pairs
#define NPAIR (Bn * 2)        // 32768
#define SBLK 64               // scan blocks (512 thr each)

typedef __attribute__((ext_vector_type(8))) short bf16x8;
typedef __attribute__((ext_vector_type(4))) float f32x4;

typedef __attribute__((address_space(3))) unsigned lds_u;
typedef __attribute__((address_space(1))) const unsigned glb_u;
// async global->LDS, 16B per lane; LDS dest = wave-uniform base + lane*16
__device__ __forceinline__ void cp16(const unsigned short* g, void* l) {
  __builtin_amdgcn_global_load_lds((glb_u*)g, (lds_u*)l, 16, 0, 0);
}

// bijective XCD-aware remap (T1); valid since our grids are multiples of 8
__device__ __forceinline__ int xcd_swz(int orig, int nwg) {
  int q = nwg >> 3;
  return (orig & 7) * q + (orig >> 3);
}

__device__ __forceinline__ unsigned short f2bf(float f) {
  union { float f; unsigned u; } v; v.f = f;
  unsigned r = v.u + 0x7FFFu + ((v.u >> 16) & 1u);   // RNE
  return (unsigned short)(r >> 16);
}
__device__ __forceinline__ float bf2f(short s) {
  union { unsigned u; float f; } v; v.u = ((unsigned)(unsigned short)s) << 16; return v.f;
}

// ------- fused transpose+convert for BOTH weights in one launch -------
// bid < 4096: w1 [Dn][Hn] -> w1t [Hn][Dn];  else: w2 [Hn][On] -> w2t [On][Hn]
__global__ __launch_bounds__(256) void k_transpose2(const float* __restrict__ w1,
    const float* __restrict__ w2, unsigned short* __restrict__ w1t,
    unsigned short* __restrict__ w2t) {
  __shared__ float tile[32][33];
  int bid = blockIdx.x;
  const float* s; unsigned short* d; int R, C, c0, r0, ez;
  if (bid < 4096) {
    ez = bid >> 9; int tl = bid & 511;
    R = Dn; C = Hn; c0 = (tl & 31) * 32; r0 = (tl >> 5) * 32;
    s = w1; d = w1t;
  } else {
    ez = (bid - 4096) >> 9; int tl = bid & 511;
    R = Hn; C = On; c0 = (tl & 15) * 32; r0 = (tl >> 4) * 32;
    s = w2; d = w2t;
  }
  const float* se = s + (size_t)ez * R * C;
  unsigned short* de = d + (size_t)ez * R * C;
  int tx = threadIdx.x, ty = threadIdx.y;
#pragma unroll
  for (int i = 0; i < 32; i += 8)
    tile[ty + i][tx] = se[(size_t)(r0 + ty + i) * C + (c0 + tx)];
  __syncthreads();
#pragma unroll
  for (int i = 0; i < 32; i += 8)
    de[(size_t)(c0 + ty + i) * R + (r0 + tx)] = f2bf(tile[tx][ty + i]);
}

// -------- gate: fp64 dot (exact ordering) + register-only fp32 tail, NO ATOMICS --------
// also converts its x row to bf16 (replaces the separate convert kernel)
__global__ __launch_bounds__(256) void k_gate(const float* __restrict__ x,
    const float* __restrict__ gw, const float* __restrict__ gb,
    unsigned short* __restrict__ xb,
    float* __restrict__ raw_out, float* __restrict__ idx_out,
    int* __restrict__ top_e, float* __restrict__ top_w,
    float* __restrict__ entp) {
  int lane = threadIdx.x & 63, wid = threadIdx.x >> 6;
  int t = blockIdx.x * 4 + wid;
  __shared__ float ent_s[4];
  const float* xr = x + (size_t)t * Dn + lane * 8;
  f32x4 x0 = *(const f32x4*)xr;
  f32x4 x1 = *(const f32x4*)(xr + 4);
  // fused x -> bf16 (16 B per lane, full row per wave)
  ushort4 cv0, cv1;
  cv0.x = f2bf(x0[0]); cv0.y = f2bf(x0[1]); cv0.z = f2bf(x0[2]); cv0.w = f2bf(x0[3]);
  cv1.x = f2bf(x1[0]); cv1.y = f2bf(x1[1]); cv1.z = f2bf(x1[2]); cv1.w = f2bf(x1[3]);
  unsigned short* xbr = xb + (size_t)t * Dn + lane * 8;
  *(ushort4*)xbr = cv0;
  *(ushort4*)(xbr + 4) = cv1;
  double acc[8];
#pragma unroll
  for (int e = 0; e < 8; ++e) acc[e] = 0.0;
#pragma unroll
  for (int j = 0; j < 8; ++j) {
    float xv = (j < 4) ? x0[j] : x1[j - 4];
    const float* wr = gw + (size_t)(lane * 8 + j) * 8;
    f32x4 w0 = *(const f32x4*)wr;
    f32x4 w1 = *(const f32x4*)(wr + 4);
    double xd = (double)xv;
    acc[0] += xd * (double)w0[0]; acc[1] += xd * (double)w0[1];
    acc[2] += xd * (double)w0[2]; acc[3] += xd * (double)w0[3];
    acc[4] += xd * (double)w1[0]; acc[5] += xd * (double)w1[1];
    acc[6] += xd * (double)w1[2]; acc[7] += xd * (double)w1[3];
  }
#pragma unroll
  for (int off = 32; off; off >>= 1)
#pragma unroll
    for (int e = 0; e < 8; ++e) acc[e] += __shfl_xor(acc[e], off, 64);
  double raw[8];
#pragma unroll
  for (int e = 0; e < 8; ++e) raw[e] = acc[e] + (double)gb[e];
  // branchless top-2 (fp64 compares, strict > : ties -> lower index, matches lax.top_k)
  double v0 = raw[0], v1 = -1e300;
  int i0 = 0, i1 = 0;
#pragma unroll
  for (int e = 1; e < 8; ++e) {
    bool g0 = raw[e] > v0;
    bool g1 = raw[e] > v1;
    double nv1 = g0 ? v0 : (g1 ? raw[e] : v1);
    int    ni1 = g0 ? i0 : (g1 ? e      : i1);
    v1 = nv1; i1 = ni1;
    v0 = g0 ? raw[e] : v0;
    i0 = g0 ? e      : i0;
  }
  float pf[8], s = 0.f;
#pragma unroll
  for (int e = 0; e < 8; ++e) { pf[e] = __expf((float)(raw[e] - v0)); s += pf[e]; }
  float inv = 1.f / s, ent = 0.f;
#pragma unroll
  for (int e = 0; e < 8; ++e) { float p = pf[e] * inv; ent -= p * __logf(p + 1e-9f); }
  float p0 = inv;
  float p1 = __expf((float)(v1 - v0)) * inv;
  float cw0 = 1.f / (1.f + __expf(p1 - p0));       // softmax over top-2 PROBS
  if (lane == 0) {
    f32x4 ra, rb;
    ra[0] = (float)raw[0]; ra[1] = (float)raw[1]; ra[2] = (float)raw[2]; ra[3] = (float)raw[3];
    rb[0] = (float)raw[4]; rb[1] = (float)raw[5]; rb[2] = (float)raw[6]; rb[3] = (float)raw[7];
    *(f32x4*)(raw_out + (size_t)t * 8) = ra;
    *(f32x4*)(raw_out + (size_t)t * 8 + 4) = rb;
    idx_out[t * 2 + 0] = (float)i0; idx_out[t * 2 + 1] = (float)i1;
    top_e[t * 2 + 0] = i0; top_e[t * 2 + 1] = i1;
    top_w[t * 2 + 0] = cw0; top_w[t * 2 + 1] = 1.f - cw0;
    ent_s[wid] = ent;
  }
  __syncthreads();
  if (threadIdx.x == 0) entp[blockIdx.x] = (ent_s[0] + ent_s[1]) + (ent_s[2] + ent_s[3]);
}

// ---------- atomic-free routing: ballot histogram -> scan -> ranked scatter ----------
__global__ __launch_bounds__(512) void k_hist(const int* __restrict__ top_e,
                                              int* __restrict__ bc) {
  int p = blockIdx.x * 512 + threadIdx.x;
  int lane = threadIdx.x & 63, w = threadIdx.x >> 6;
  int e = top_e[p];
  __shared__ int wc[8][8];
#pragma unroll
  for (int v = 0; v < 8; ++v) {
    unsigned long long m = __ballot(e == v);
    if (lane == 0) wc[w][v] = __popcll(m);
  }
  __syncthreads();
  if (threadIdx.x < 8) {
    int sum = 0;
#pragma unroll
    for (int w2 = 0; w2 < 8; ++w2) sum += wc[w2][threadIdx.x];
    bc[blockIdx.x * 8 + threadIdx.x] = sum;
  }
}

// 1 block, 512 threads: wave = expert, lane = scan-block; also finalizes entropy.
// tok padding is handled by hipMemsetAsync(tok, 0) at launch (token 0: harmless compute,
// padded rows are never read by k_combine).
__global__ __launch_bounds__(512) void k_offsets(const int* __restrict__ bc,
    int* __restrict__ ob, int* __restrict__ tile_expert,
    const float* __restrict__ entp, float* __restrict__ ent_out) {
  int lane = threadIdx.x & 63;     // scan-block b
  int e = threadIdx.x >> 6;        // expert
  int v = bc[lane * 8 + e];
  int sum = v;
#pragma unroll
  for (int off = 1; off < 64; off <<= 1) {
    int o = __shfl_up(sum, off, 64);
    if (lane >= off) sum += o;
  }
  int excl = sum - v;
  __shared__ int tot8[8], po[9];
  __shared__ float es[512];
  // entropy finalize (independent of the scan)
  float ev = 0.f;
  for (int i = threadIdx.x; i < 4096; i += 512) ev += entp[i];
  es[threadIdx.x] = ev;
  if (lane == 63) tot8[e] = sum;
  __syncthreads();
  for (int o = 256; o; o >>= 1) {
    if (threadIdx.x < o) es[threadIdx.x] += es[threadIdx.x + o];
    __syncthreads();
  }
  if (threadIdx.x == 0) ent_out[0] = es[0] / (float)Bn;
  int seg = 0;
#pragma unroll
  for (int e2 = 0; e2 < 8; ++e2) {
    int padded = ((tot8[e2] + 127) >> 7) << 7;
    seg += (e2 < e) ? padded : 0;
  }
  ob[lane * 8 + e] = seg + excl;
  if (lane == 0) po[e] = seg;
  if (threadIdx.x == 511) po[8] = seg + (((tot8[7] + 127) >> 7) << 7);
  __syncthreads();
  for (int i = threadIdx.x; i < MTILES; i += 512) {
    int base = i * 128, ee = -1;
#pragma unroll
    for (int j = 0; j < 8; ++j) if (base >= po[j] && base < po[j + 1]) ee = j;
    tile_expert[i] = ee;
  }
}

__global__ __launch_bounds__(512) void k_scatter2(const int* __restrict__ top_e,
    const float* __restrict__ top_w, const int* __restrict__ ob,
    int* __restrict__ tok, int* __restrict__ pos_tk) {
  int p = blockIdx.x * 512 + threadIdx.x;
  int lane = threadIdx.x & 63, w = threadIdx.x >> 6;
  int e = top_e[p];
  __shared__ int wc[8][8];
  unsigned long long lt = (1ULL << lane) - 1;
  int rank = 0;
#pragma unroll
  for (int v = 0; v < 8; ++v) {
    unsigned long long m = __ballot(e == v);
    if (lane == 0) wc[w][v] = __popcll(m);
    if (e == v) rank = __popcll(m & lt);
  }
  __syncthreads();
  int wpre = 0;
#pragma unroll
  for (int w2 = 0; w2 < 8; ++w2) wpre += (w2 < w) ? wc[w2][e] : 0;   // LDS runtime idx ok
  int pos = ob[blockIdx.x * 8 + e] + wpre + rank;
  tok[pos] = p >> 1;
  pos_tk[p] = pos;
}

// ============ GEMM1: h[pair][H] = relu(x[tok]·w1[e] + b1[e]), 128x128 tile ============
// R9-proven: single-buffer 2-barrier K-loop, 4 waves, XCD swizzle, global_load_lds(16B)
__global__ __launch_bounds__(256) void k_gemm1(const unsigned short* __restrict__ xb,
    const unsigned short* __restrict__ w1t, const float* __restrict__ b1,
    const int* __restrict__ tok, const int* __restrict__ tile_expert,
    unsigned short* __restrict__ h) {
  const int wg = xcd_swz(blockIdx.x, MTILES * (Hn / 128));
  const int mt = wg >> 3, nb = wg & 7;
  int e = tile_expert[mt];
  if (e < 0) return;
  const int m0 = mt * 128, n0 = nb * 128;
  __shared__ char As[16384];
  __shared__ char Bs[16384];
  const int tid = threadIdx.x, lane = tid & 63, wv = tid >> 6;
  const int wm = wv >> 1, wn = wv & 1;
  const int rA = tid >> 3;
  const int c8 = ((tid & 7) ^ ((tid >> 3) & 7)) * 8;
  int trow[4];
#pragma unroll
  for (int i = 0; i < 4; ++i) trow[i] = tok[m0 + i * 32 + rA];
  const unsigned short* w1e = w1t + (size_t)e * Hn * Dn;
  f32x4 acc[4][4];
#pragma unroll
  for (int m = 0; m < 4; ++m)
#pragma unroll
    for (int n = 0; n < 4; ++n) acc[m][n] = (f32x4){0.f, 0.f, 0.f, 0.f};

  for (int kt = 0; kt < Dn / 64; ++kt) {
    const int k0 = kt * 64;
    if (kt) __syncthreads();
#pragma unroll
    for (int i = 0; i < 4; ++i)
      cp16(xb + (size_t)trow[i] * Dn + k0 + c8, As + i * 4096 + wv * 1024);
#pragma unroll
    for (int i = 0; i < 4; ++i)
      cp16(w1e + (size_t)(n0 + i * 32 + rA) * Dn + k0 + c8, Bs + i * 4096 + wv * 1024);
    __syncthreads();
#pragma unroll
    for (int kk = 0; kk < 2; ++kk) {
      const int bc = kk * 64 + (lane >> 4) * 16;
      bf16x8 a[4], b[4];
#pragma unroll
      for (int m = 0; m < 4; ++m) {
        int r = wm * 64 + m * 16 + (lane & 15);
        a[m] = *(const bf16x8*)(As + r * 128 + (bc ^ ((r & 7) << 4)));
      }
#pragma unroll
      for (int n = 0; n < 4; ++n) {
        int r = wn * 64 + n * 16 + (lane & 15);
        b[n] = *(const bf16x8*)(Bs + r * 128 + (bc ^ ((r & 7) << 4)));
      }
#pragma unroll
      for (int m = 0; m < 4; ++m)
#pragma unroll
        for (int n = 0; n < 4; ++n)
          acc[m][n] = __builtin_amdgcn_mfma_f32_16x16x32_bf16(a[m], b[n], acc[m][n], 0, 0, 0);
    }
  }
#pragma unroll
  for (int n = 0; n < 4; ++n) {
    int gcol = n0 + wn * 64 + n * 16 + (lane & 15);
    float bias = b1[e * Hn + gcol];
#pragma unroll
    for (int m = 0; m < 4; ++m) {
      int grow = m0 + wm * 64 + m * 16 + ((lane >> 4) << 2);
#pragma unroll
      for (int r = 0; r < 4; ++r) {
        float v = fmaxf(acc[m][n][r] + bias, 0.f);
        h[(size_t)(grow + r) * Hn + gcol] = f2bf(v);
      }
    }
  }
}

// ============ GEMM2: y[pair][O] = h·w2[e] + b2[e] (bf16), 128x128 tile ============
__global__ __launch_bounds__(256) void k_gemm2(const unsigned short* __restrict__ h,
    const unsigned short* __restrict__ w2t, const float* __restrict__ b2,
    const int* __restrict__ tile_expert, unsigned short* __restrict__ y) {
  const int wg = xcd_swz(blockIdx.x, MTILES * (On / 128));
  const int mt = wg >> 2, nb = wg & 3;
  int e = tile_expert[mt];
  if (e < 0) return;
  const int m0 = mt * 128, n0 = nb * 128;
  __shared__ char As[16384];
  __shared__ char Bs[16384];
  const int tid = threadIdx.x, lane = tid & 63, wv = tid >> 6;
  const int wm = wv >> 1, wn = wv & 1;
  const int rA = tid >> 3;
  const int c8 = ((tid & 7) ^ ((tid >> 3) & 7)) * 8;
  const unsigned short* w2e = w2t + (size_t)e * On * Hn;
  f32x4 acc[4][4];
#pragma unroll
  for (int m = 0; m < 4; ++m)
#pragma unroll
    for (int n = 0; n < 4; ++n) acc[m][n] = (f32x4){0.f, 0.f, 0.f, 0.f};

  for (int kt = 0; kt < Hn / 64; ++kt) {
    const int k0 = kt * 64;
    if (kt) __syncthreads();
#pragma unroll
    for (int i = 0; i < 4; ++i)
      cp16(h + (size_t)(m0 + i * 32 + rA) * Hn + k0 + c8, As + i * 4096 + wv * 1024);
#pragma unroll
    for (int i = 0; i < 4; ++i)
      cp16(w2e + (size_t)(n0 + i * 32 + rA) * Hn + k0 + c8, Bs + i * 4096 + wv * 1024);
    __syncthreads();
#pragma unroll
    for (int kk = 0; kk < 2; ++kk) {
      const int bc = kk * 64 + (lane >> 4) * 16;
      bf16x8 a[4], b[4];
#pragma unroll
      for (int m = 0; m < 4; ++m) {
        int r = wm * 64 + m * 16 + (lane & 15);
        a[m] = *(const bf16x8*)(As + r * 128 + (bc ^ ((r & 7) << 4)));
      }
#pragma unroll
      for (int n = 0; n < 4; ++n) {
        int r = wn * 64 + n * 16 + (lane & 15);
        b[n] = *(const bf16x8*)(Bs + r * 128 + (bc ^ ((r & 7) << 4)));
      }
#pragma unroll
      for (int m = 0; m < 4; ++m)
#pragma unroll
        for (int n = 0; n < 4; ++n)
          acc[m][n] = __builtin_amdgcn_mfma_f32_16x16x32_bf16(a[m], b[n], acc[m][n], 0, 0, 0);
    }
  }
#pragma unroll
  for (int n = 0; n < 4; ++n) {
    int gcol = n0 + wn * 64 + n * 16 + (lane & 15);
    float bias = b2[e * On + gcol];
#pragma unroll
    for (int m = 0; m < 4; ++m) {
      int grow = m0 + wm * 64 + m * 16 + ((lane >> 4) << 2);
#pragma unroll
      for (int r = 0; r < 4; ++r)
        y[(size_t)(grow + r) * On + gcol] = f2bf(acc[m][n][r] + bias);
    }
  }
}

// ---------------- combine: out[t] = w0*y[p0] + w1*y[p1] ----------------
__global__ __launch_bounds__(256) void k_combine(const unsigned short* __restrict__ y,
    const int* __restrict__ pos_tk, const float* __restrict__ top_w,
    float* __restrict__ out) {
  int wid = threadIdx.x >> 6, lane = threadIdx.x & 63;
  int t = blockIdx.x * 4 + wid;
  int p0 = pos_tk[t * 2], p1 = pos_tk[t * 2 + 1];
  float w0 = top_w[t * 2], w1 = top_w[t * 2 + 1];
  bf16x8 a = *(const bf16x8*)(y + (size_t)p0 * On + lane * 8);
  bf16x8 b = *(const bf16x8*)(y + (size_t)p1 * On + lane * 8);
  f32x4 o0, o1;
#pragma unroll
  for (int j = 0; j < 4; ++j) {
    o0[j] = w0 * bf2f(a[j]) + w1 * bf2f(b[j]);
    o1[j] = w0 * bf2f(a[j + 4]) + w1 * bf2f(b[j + 4]);
  }
  float* op = out + (size_t)t * On + lane * 8;
  *(f32x4*)op = o0;
  *(f32x4*)(op + 4) = o1;
}

extern "C" void kernel_launch(void* const* d_in, const int* in_sizes, int n_in,
                              void* d_out, int out_size, void* d_ws, size_t ws_size,
                              hipStream_t stream) {
  const float* x  = (const float*)d_in[0];
  const float* gw = (const float*)d_in[1];
  const float* gb = (const float*)d_in[2];
  const float* w1 = (const float*)d_in[3];
  const float* b1 = (const float*)d_in[4];
  const float* w2 = (const float*)d_in[5];
  const float* b2 = (const float*)d_in[6];
  float* out     = (float*)d_out;
  float* raw_out = out + (size_t)Bn * On;
  float* idx_out = raw_out + (size_t)Bn * En;
  float* ent_out = idx_out + (size_t)Bn * 2;

  char* ws = (char*)d_ws;
  size_t off = 0;
  auto alloc = [&](size_t bytes) { char* p = ws + off; off += (bytes + 255) & ~(size_t)255; return p; };
  unsigned short* xb   = (unsigned short*)alloc((size_t)Bn * Dn * 2);
  unsigned short* w1t  = (unsigned short*)alloc((size_t)En * Hn * Dn * 2);
  unsigned short* w2t  = (unsigned short*)alloc((size_t)En * On * Hn * 2);
  unsigned short* hbuf = (unsigned short*)alloc((size_t)MAXP * Hn * 2);
  unsigned short* ybuf = (unsigned short*)alloc((size_t)MAXP * On * 2);
  int*   tok    = (int*)alloc((size_t)MAXP * 4);
  int*   pos_tk = (int*)alloc((size_t)NPAIR * 4);
  int*   top_e  = (int*)alloc((size_t)NPAIR * 4);
  float* top_w  = (float*)alloc((size_t)NPAIR * 4);
  int*   bc     = (int*)alloc(SBLK * 8 * 4);
  int*   ob     = (int*)alloc(SBLK * 8 * 4);
  int*   tile_expert = (int*)alloc(MTILES * 4);
  float* entp   = (float*)alloc(4096 * 4);

  // padding rows of tok -> token 0 (harmless: padded h/y rows are never read)
  hipMemsetAsync(tok, 0, (size_t)MAXP * 4, stream);

  k_transpose2<<<8192, dim3(32, 8), 0, stream>>>(w1, w2, w1t, w2t);
  k_gate<<<Bn / 4, 256, 0, stream>>>(x, gw, gb, xb, raw_out, idx_out, top_e, top_w, entp);
  k_hist<<<SBLK, 512, 0, stream>>>(top_e, bc);
  k_offsets<<<1, 512, 0, stream>>>(bc, ob, tile_expert, entp, ent_out);
  k_scatter2<<<SBLK, 512, 0, stream>>>(top_e, top_w, ob, tok, pos_tk);
  k_gemm1<<<MTILES * (Hn / 128), 256, 0, stream>>>(xb, w1t, b1, tok, tile_expert, hbuf);
  k_gemm2<<<MTILES * (On / 128), 256, 0, stream>>>(hbuf, w2t, b2, tile_expert, ybuf);
  k_combine<<<Bn / 4, 256, 0, stream>>>(ybuf, pos_tk, top_w, out);
}

// Round 15
// 157.034 us; speedup vs baseline: 1.3744x; 1.0257x over previous
//
#include <hip/hip_runtime.h>
#include <hip/hip_bf16.h>

#define Bn 16384
#define Dn 512
#define Hn 1024
#define On 512
#define En 8
#define MTILES 264            // ceil((32768 + 8*127)/128)
#define MAXP (MTILES * 128)   // 33792 padded token-expert pairs
#define NPAIR (Bn * 2)        // 32768
#define SBLK 64               // scan blocks (512 thr each)

typedef __attribute__((ext_vector_type(8))) short bf16x8;
typedef __attribute__((ext_vector_type(4))) float f32x4;

typedef __attribute__((address_space(3))) unsigned lds_u;
typedef __attribute__((address_space(1))) const unsigned glb_u;
// async global->LDS, 16B per lane; LDS dest = wave-uniform base + lane*16
__device__ __forceinline__ void cp16(const unsigned short* g, void* l) {
  __builtin_amdgcn_global_load_lds((glb_u*)g, (lds_u*)l, 16, 0, 0);
}

// bijective XCD-aware remap (T1); valid since our grids are multiples of 8
__device__ __forceinline__ int xcd_swz(int orig, int nwg) {
  int q = nwg >> 3;
  return (orig & 7) * q + (orig >> 3);
}

__device__ __forceinline__ unsigned short f2bf(float f) {
  union { float f; unsigned u; } v; v.f = f;
  unsigned r = v.u + 0x7FFFu + ((v.u >> 16) & 1u);   // RNE
  return (unsigned short)(r >> 16);
}
__device__ __forceinline__ float bf2f(short s) {
  union { unsigned u; float f; } v; v.u = ((unsigned)(unsigned short)s) << 16; return v.f;
}

// ======== prep (fused): gate (bid<4096) + weight transpose (bid>=4096) ========
// gate: fp64 dot (exact top-k ordering) + register-only fp32 tail, no atomics;
//       also converts its x row to bf16.
// transpose: w1 [Dn][Hn] -> w1t [Hn][Dn]; w2 [Hn][On] -> w2t [On][Hn] (bf16).
// Independent work fused into one launch so transpose's pure-BW traffic overlaps
// gate's fp64 VALU phase (and one launch gap is removed).
__global__ __launch_bounds__(256) void k_prep(const float* __restrict__ x,
    const float* __restrict__ gw, const float* __restrict__ gb,
    const float* __restrict__ w1, const float* __restrict__ w2,
    unsigned short* __restrict__ xb,
    unsigned short* __restrict__ w1t, unsigned short* __restrict__ w2t,
    float* __restrict__ raw_out, float* __restrict__ idx_out,
    int* __restrict__ top_e, float* __restrict__ top_w,
    float* __restrict__ entp) {
  __shared__ float tile[32][33];
  __shared__ float ent_s[4];
  int bid = blockIdx.x;
  if (bid >= 4096) {
    // ---------------- transpose branch ----------------
    int tb = bid - 4096;
    const float* s; unsigned short* d; int R, C, c0, r0, ez;
    if (tb < 4096) {
      ez = tb >> 9; int tl = tb & 511;
      R = Dn; C = Hn; c0 = (tl & 31) * 32; r0 = (tl >> 5) * 32;
      s = w1; d = w1t;
    } else {
      ez = (tb - 4096) >> 9; int tl = tb & 511;
      R = Hn; C = On; c0 = (tl & 15) * 32; r0 = (tl >> 4) * 32;
      s = w2; d = w2t;
    }
    const float* se = s + (size_t)ez * R * C;
    unsigned short* de = d + (size_t)ez * R * C;
    int tx = threadIdx.x & 31, ty = threadIdx.x >> 5;
#pragma unroll
    for (int i = 0; i < 32; i += 8)
      tile[ty + i][tx] = se[(size_t)(r0 + ty + i) * C + (c0 + tx)];
    __syncthreads();
#pragma unroll
    for (int i = 0; i < 32; i += 8)
      de[(size_t)(c0 + ty + i) * R + (r0 + tx)] = f2bf(tile[tx][ty + i]);
    return;
  }
  // ---------------- gate branch ----------------
  int lane = threadIdx.x & 63, wid = threadIdx.x >> 6;
  int t = bid * 4 + wid;
  const float* xr = x + (size_t)t * Dn + lane * 8;
  f32x4 x0 = *(const f32x4*)xr;
  f32x4 x1 = *(const f32x4*)(xr + 4);
  // fused x -> bf16 (16 B per lane, full row per wave)
  ushort4 cv0, cv1;
  cv0.x = f2bf(x0[0]); cv0.y = f2bf(x0[1]); cv0.z = f2bf(x0[2]); cv0.w = f2bf(x0[3]);
  cv1.x = f2bf(x1[0]); cv1.y = f2bf(x1[1]); cv1.z = f2bf(x1[2]); cv1.w = f2bf(x1[3]);
  unsigned short* xbr = xb + (size_t)t * Dn + lane * 8;
  *(ushort4*)xbr = cv0;
  *(ushort4*)(xbr + 4) = cv1;
  double acc[8];
#pragma unroll
  for (int e = 0; e < 8; ++e) acc[e] = 0.0;
#pragma unroll
  for (int j = 0; j < 8; ++j) {
    float xv = (j < 4) ? x0[j] : x1[j - 4];
    const float* wr = gw + (size_t)(lane * 8 + j) * 8;
    f32x4 w0 = *(const f32x4*)wr;
    f32x4 w1v = *(const f32x4*)(wr + 4);
    double xd = (double)xv;
    acc[0] += xd * (double)w0[0]; acc[1] += xd * (double)w0[1];
    acc[2] += xd * (double)w0[2]; acc[3] += xd * (double)w0[3];
    acc[4] += xd * (double)w1v[0]; acc[5] += xd * (double)w1v[1];
    acc[6] += xd * (double)w1v[2]; acc[7] += xd * (double)w1v[3];
  }
#pragma unroll
  for (int off = 32; off; off >>= 1)
#pragma unroll
    for (int e = 0; e < 8; ++e) acc[e] += __shfl_xor(acc[e], off, 64);
  double raw[8];
#pragma unroll
  for (int e = 0; e < 8; ++e) raw[e] = acc[e] + (double)gb[e];
  // branchless top-2 (fp64 compares, strict > : ties -> lower index, matches lax.top_k)
  double v0 = raw[0], v1 = -1e300;
  int i0 = 0, i1 = 0;
#pragma unroll
  for (int e = 1; e < 8; ++e) {
    bool g0 = raw[e] > v0;
    bool g1 = raw[e] > v1;
    double nv1 = g0 ? v0 : (g1 ? raw[e] : v1);
    int    ni1 = g0 ? i0 : (g1 ? e      : i1);
    v1 = nv1; i1 = ni1;
    v0 = g0 ? raw[e] : v0;
    i0 = g0 ? e      : i0;
  }
  float pf[8], s = 0.f;
#pragma unroll
  for (int e = 0; e < 8; ++e) { pf[e] = __expf((float)(raw[e] - v0)); s += pf[e]; }
  float inv = 1.f / s, ent = 0.f;
#pragma unroll
  for (int e = 0; e < 8; ++e) { float p = pf[e] * inv; ent -= p * __logf(p + 1e-9f); }
  float p0 = inv;
  float p1 = __expf((float)(v1 - v0)) * inv;
  float cw0 = 1.f / (1.f + __expf(p1 - p0));       // softmax over top-2 PROBS
  if (lane == 0) {
    f32x4 ra, rb;
    ra[0] = (float)raw[0]; ra[1] = (float)raw[1]; ra[2] = (float)raw[2]; ra[3] = (float)raw[3];
    rb[0] = (float)raw[4]; rb[1] = (float)raw[5]; rb[2] = (float)raw[6]; rb[3] = (float)raw[7];
    *(f32x4*)(raw_out + (size_t)t * 8) = ra;
    *(f32x4*)(raw_out + (size_t)t * 8 + 4) = rb;
    idx_out[t * 2 + 0] = (float)i0; idx_out[t * 2 + 1] = (float)i1;
    top_e[t * 2 + 0] = i0; top_e[t * 2 + 1] = i1;
    top_w[t * 2 + 0] = cw0; top_w[t * 2 + 1] = 1.f - cw0;
    ent_s[wid] = ent;
  }
  __syncthreads();
  if (threadIdx.x == 0) entp[bid] = (ent_s[0] + ent_s[1]) + (ent_s[2] + ent_s[3]);
}

// ---------- atomic-free routing: ballot histogram -> scan -> ranked scatter ----------
__global__ __launch_bounds__(512) void k_hist(const int* __restrict__ top_e,
                                              int* __restrict__ bc) {
  int p = blockIdx.x * 512 + threadIdx.x;
  int lane = threadIdx.x & 63, w = threadIdx.x >> 6;
  int e = top_e[p];
  __shared__ int wc[8][8];
#pragma unroll
  for (int v = 0; v < 8; ++v) {
    unsigned long long m = __ballot(e == v);
    if (lane == 0) wc[w][v] = __popcll(m);
  }
  __syncthreads();
  if (threadIdx.x < 8) {
    int sum = 0;
#pragma unroll
    for (int w2 = 0; w2 < 8; ++w2) sum += wc[w2][threadIdx.x];
    bc[blockIdx.x * 8 + threadIdx.x] = sum;
  }
}

// 1 block, 512 threads: wave = expert, lane = scan-block; also finalizes entropy.
// tok padding is handled by hipMemsetAsync(tok, 0) at launch (token 0: harmless compute,
// padded rows are never read by k_combine).
__global__ __launch_bounds__(512) void k_offsets(const int* __restrict__ bc,
    int* __restrict__ ob, int* __restrict__ tile_expert,
    const float* __restrict__ entp, float* __restrict__ ent_out) {
  int lane = threadIdx.x & 63;     // scan-block b
  int e = threadIdx.x >> 6;        // expert
  int v = bc[lane * 8 + e];
  int sum = v;
#pragma unroll
  for (int off = 1; off < 64; off <<= 1) {
    int o = __shfl_up(sum, off, 64);
    if (lane >= off) sum += o;
  }
  int excl = sum - v;
  __shared__ int tot8[8], po[9];
  __shared__ float es[512];
  // entropy finalize (independent of the scan)
  float ev = 0.f;
  for (int i = threadIdx.x; i < 4096; i += 512) ev += entp[i];
  es[threadIdx.x] = ev;
  if (lane == 63) tot8[e] = sum;
  __syncthreads();
  for (int o = 256; o; o >>= 1) {
    if (threadIdx.x < o) es[threadIdx.x] += es[threadIdx.x + o];
    __syncthreads();
  }
  if (threadIdx.x == 0) ent_out[0] = es[0] / (float)Bn;
  int seg = 0;
#pragma unroll
  for (int e2 = 0; e2 < 8; ++e2) {
    int padded = ((tot8[e2] + 127) >> 7) << 7;
    seg += (e2 < e) ? padded : 0;
  }
  ob[lane * 8 + e] = seg + excl;
  if (lane == 0) po[e] = seg;
  if (threadIdx.x == 511) po[8] = seg + (((tot8[7] + 127) >> 7) << 7);
  __syncthreads();
  for (int i = threadIdx.x; i < MTILES; i += 512) {
    int base = i * 128, ee = -1;
#pragma unroll
    for (int j = 0; j < 8; ++j) if (base >= po[j] && base < po[j + 1]) ee = j;
    tile_expert[i] = ee;
  }
}

__global__ __launch_bounds__(512) void k_scatter2(const int* __restrict__ top_e,
    const float* __restrict__ top_w, const int* __restrict__ ob,
    int* __restrict__ tok, int* __restrict__ pos_tk) {
  int p = blockIdx.x * 512 + threadIdx.x;
  int lane = threadIdx.x & 63, w = threadIdx.x >> 6;
  int e = top_e[p];
  __shared__ int wc[8][8];
  unsigned long long lt = (1ULL << lane) - 1;
  int rank = 0;
#pragma unroll
  for (int v = 0; v < 8; ++v) {
    unsigned long long m = __ballot(e == v);
    if (lane == 0) wc[w][v] = __popcll(m);
    if (e == v) rank = __popcll(m & lt);
  }
  __syncthreads();
  int wpre = 0;
#pragma unroll
  for (int w2 = 0; w2 < 8; ++w2) wpre += (w2 < w) ? wc[w2][e] : 0;   // LDS runtime idx ok
  int pos = ob[blockIdx.x * 8 + e] + wpre + rank;
  tok[pos] = p >> 1;
  pos_tk[p] = pos;
}

// ============ GEMM1: h[pair][H] = relu(x[tok]·w1[e] + b1[e]), 128x128 tile ============
// R9-proven: single-buffer 2-barrier K-loop, 4 waves, XCD swizzle, global_load_lds(16B)
__global__ __launch_bounds__(256) void k_gemm1(const unsigned short* __restrict__ xb,
    const unsigned short* __restrict__ w1t, const float* __restrict__ b1,
    const int* __restrict__ tok, const int* __restrict__ tile_expert,
    unsigned short* __restrict__ h) {
  const int wg = xcd_swz(blockIdx.x, MTILES * (Hn / 128));
  const int mt = wg >> 3, nb = wg & 7;
  int e = tile_expert[mt];
  if (e < 0) return;
  const int m0 = mt * 128, n0 = nb * 128;
  __shared__ char As[16384];
  __shared__ char Bs[16384];
  const int tid = threadIdx.x, lane = tid & 63, wv = tid >> 6;
  const int wm = wv >> 1, wn = wv & 1;
  const int rA = tid >> 3;
  const int c8 = ((tid & 7) ^ ((tid >> 3) & 7)) * 8;
  int trow[4];
#pragma unroll
  for (int i = 0; i < 4; ++i) trow[i] = tok[m0 + i * 32 + rA];
  const unsigned short* w1e = w1t + (size_t)e * Hn * Dn;
  f32x4 acc[4][4];
#pragma unroll
  for (int m = 0; m < 4; ++m)
#pragma unroll
    for (int n = 0; n < 4; ++n) acc[m][n] = (f32x4){0.f, 0.f, 0.f, 0.f};

  for (int kt = 0; kt < Dn / 64; ++kt) {
    const int k0 = kt * 64;
    if (kt) __syncthreads();
#pragma unroll
    for (int i = 0; i < 4; ++i)
      cp16(xb + (size_t)trow[i] * Dn + k0 + c8, As + i * 4096 + wv * 1024);
#pragma unroll
    for (int i = 0; i < 4; ++i)
      cp16(w1e + (size_t)(n0 + i * 32 + rA) * Dn + k0 + c8, Bs + i * 4096 + wv * 1024);
    __syncthreads();
#pragma unroll
    for (int kk = 0; kk < 2; ++kk) {
      const int bc = kk * 64 + (lane >> 4) * 16;
      bf16x8 a[4], b[4];
#pragma unroll
      for (int m = 0; m < 4; ++m) {
        int r = wm * 64 + m * 16 + (lane & 15);
        a[m] = *(const bf16x8*)(As + r * 128 + (bc ^ ((r & 7) << 4)));
      }
#pragma unroll
      for (int n = 0; n < 4; ++n) {
        int r = wn * 64 + n * 16 + (lane & 15);
        b[n] = *(const bf16x8*)(Bs + r * 128 + (bc ^ ((r & 7) << 4)));
      }
#pragma unroll
      for (int m = 0; m < 4; ++m)
#pragma unroll
        for (int n = 0; n < 4; ++n)
          acc[m][n] = __builtin_amdgcn_mfma_f32_16x16x32_bf16(a[m], b[n], acc[m][n], 0, 0, 0);
    }
  }
#pragma unroll
  for (int n = 0; n < 4; ++n) {
    int gcol = n0 + wn * 64 + n * 16 + (lane & 15);
    float bias = b1[e * Hn + gcol];
#pragma unroll
    for (int m = 0; m < 4; ++m) {
      int grow = m0 + wm * 64 + m * 16 + ((lane >> 4) << 2);
#pragma unroll
      for (int r = 0; r < 4; ++r) {
        float v = fmaxf(acc[m][n][r] + bias, 0.f);
        h[(size_t)(grow + r) * Hn + gcol] = f2bf(v);
      }
    }
  }
}

// ============ GEMM2: y[pair][O] = h·w2[e] + b2[e] (bf16), 128x128 tile ============
__global__ __launch_bounds__(256) void k_gemm2(const unsigned short* __restrict__ h,
    const unsigned short* __restrict__ w2t, const float* __restrict__ b2,
    const int* __restrict__ tile_expert, unsigned short* __restrict__ y) {
  const int wg = xcd_swz(blockIdx.x, MTILES * (On / 128));
  const int mt = wg >> 2, nb = wg & 3;
  int e = tile_expert[mt];
  if (e < 0) return;
  const int m0 = mt * 128, n0 = nb * 128;
  __shared__ char As[16384];
  __shared__ char Bs[16384];
  const int tid = threadIdx.x, lane = tid & 63, wv = tid >> 6;
  const int wm = wv >> 1, wn = wv & 1;
  const int rA = tid >> 3;
  const int c8 = ((tid & 7) ^ ((tid >> 3) & 7)) * 8;
  const unsigned short* w2e = w2t + (size_t)e * On * Hn;
  f32x4 acc[4][4];
#pragma unroll
  for (int m = 0; m < 4; ++m)
#pragma unroll
    for (int n = 0; n < 4; ++n) acc[m][n] = (f32x4){0.f, 0.f, 0.f, 0.f};

  for (int kt = 0; kt < Hn / 64; ++kt) {
    const int k0 = kt * 64;
    if (kt) __syncthreads();
#pragma unroll
    for (int i = 0; i < 4; ++i)
      cp16(h + (size_t)(m0 + i * 32 + rA) * Hn + k0 + c8, As + i * 4096 + wv * 1024);
#pragma unroll
    for (int i = 0; i < 4; ++i)
      cp16(w2e + (size_t)(n0 + i * 32 + rA) * Hn + k0 + c8, Bs + i * 4096 + wv * 1024);
    __syncthreads();
#pragma unroll
    for (int kk = 0; kk < 2; ++kk) {
      const int bc = kk * 64 + (lane >> 4) * 16;
      bf16x8 a[4], b[4];
#pragma unroll
      for (int m = 0; m < 4; ++m) {
        int r = wm * 64 + m * 16 + (lane & 15);
        a[m] = *(const bf16x8*)(As + r * 128 + (bc ^ ((r & 7) << 4)));
      }
#pragma unroll
      for (int n = 0; n < 4; ++n) {
        int r = wn * 64 + n * 16 + (lane & 15);
        b[n] = *(const bf16x8*)(Bs + r * 128 + (bc ^ ((r & 7) << 4)));
      }
#pragma unroll
      for (int m = 0; m < 4; ++m)
#pragma unroll
        for (int n = 0; n < 4; ++n)
          acc[m][n] = __builtin_amdgcn_mfma_f32_16x16x32_bf16(a[m], b[n], acc[m][n], 0, 0, 0);
    }
  }
#pragma unroll
  for (int n = 0; n < 4; ++n) {
    int gcol = n0 + wn * 64 + n * 16 + (lane & 15);
    float bias = b2[e * On + gcol];
#pragma unroll
    for (int m = 0; m < 4; ++m) {
      int grow = m0 + wm * 64 + m * 16 + ((lane >> 4) << 2);
#pragma unroll
      for (int r = 0; r < 4; ++r)
        y[(size_t)(grow + r) * On + gcol] = f2bf(acc[m][n][r] + bias);
    }
  }
}

// ---------------- combine: out[t] = w0*y[p0] + w1*y[p1] ----------------
__global__ __launch_bounds__(256) void k_combine(const unsigned short* __restrict__ y,
    const int* __restrict__ pos_tk, const float* __restrict__ top_w,
    float* __restrict__ out) {
  int wid = threadIdx.x >> 6, lane = threadIdx.x & 63;
  int t = blockIdx.x * 4 + wid;
  int p0 = pos_tk[t * 2], p1 = pos_tk[t * 2 + 1];
  float w0 = top_w[t * 2], w1 = top_w[t * 2 + 1];
  bf16x8 a = *(const bf16x8*)(y + (size_t)p0 * On + lane * 8);
  bf16x8 b = *(const bf16x8*)(y + (size_t)p1 * On + lane * 8);
  f32x4 o0, o1;
#pragma unroll
  for (int j = 0; j < 4; ++j) {
    o0[j] = w0 * bf2f(a[j]) + w1 * bf2f(b[j]);
    o1[j] = w0 * bf2f(a[j + 4]) + w1 * bf2f(b[j + 4]);
  }
  float* op = out + (size_t)t * On + lane * 8;
  *(f32x4*)op = o0;
  *(f32x4*)(op + 4) = o1;
}

extern "C" void kernel_launch(void* const* d_in, const int* in_sizes, int n_in,
                              void* d_out, int out_size, void* d_ws, size_t ws_size,
                              hipStream_t stream) {
  const float* x  = (const float*)d_in[0];
  const float* gw = (const float*)d_in[1];
  const float* gb = (const float*)d_in[2];
  const float* w1 = (const float*)d_in[3];
  const float* b1 = (const float*)d_in[4];
  const float* w2 = (const float*)d_in[5];
  const float* b2 = (const float*)d_in[6];
  float* out     = (float*)d_out;
  float* raw_out = out + (size_t)Bn * On;
  float* idx_out = raw_out + (size_t)Bn * En;
  float* ent_out = idx_out + (size_t)Bn * 2;

  char* ws = (char*)d_ws;
  size_t off = 0;
  auto alloc = [&](size_t bytes) { char* p = ws + off; off += (bytes + 255) & ~(size_t)255; return p; };
  unsigned short* xb   = (unsigned short*)alloc((size_t)Bn * Dn * 2);
  unsigned short* w1t  = (unsigned short*)alloc((size_t)En * Hn * Dn * 2);
  unsigned short* w2t  = (unsigned short*)alloc((size_t)En * On * Hn * 2);
  unsigned short* hbuf = (unsigned short*)alloc((size_t)MAXP * Hn * 2);
  unsigned short* ybuf = (unsigned short*)alloc((size_t)MAXP * On * 2);
  int*   tok    = (int*)alloc((size_t)MAXP * 4);
  int*   pos_tk = (int*)alloc((size_t)NPAIR * 4);
  int*   top_e  = (int*)alloc((size_t)NPAIR * 4);
  float* top_w  = (float*)alloc((size_t)NPAIR * 4);
  int*   bc     = (int*)alloc(SBLK * 8 * 4);
  int*   ob     = (int*)alloc(SBLK * 8 * 4);
  int*   tile_expert = (int*)alloc(MTILES * 4);
  float* entp   = (float*)alloc(4096 * 4);

  // padding rows of tok -> token 0 (harmless: padded h/y rows are never read)
  hipMemsetAsync(tok, 0, (size_t)MAXP * 4, stream);

  k_prep<<<12288, 256, 0, stream>>>(x, gw, gb, w1, w2, xb, w1t, w2t,
                                    raw_out, idx_out, top_e, top_w, entp);
  k_hist<<<SBLK, 512, 0, stream>>>(top_e, bc);
  k_offsets<<<1, 512, 0, stream>>>(bc, ob, tile_expert, entp, ent_out);
  k_scatter2<<<SBLK, 512, 0, stream>>>(top_e, top_w, ob, tok, pos_tk);
  k_gemm1<<<MTILES * (Hn / 128), 256, 0, stream>>>(xb, w1t, b1, tok, tile_expert, hbuf);
  k_gemm2<<<MTILES * (On / 128), 256, 0, stream>>>(hbuf, w2t, b2, tile_expert, ybuf);
  k_combine<<<Bn / 4, 256, 0, stream>>>(ybuf, pos_tk, top_w, out);
}

// Round 16
// 156.051 us; speedup vs baseline: 1.3831x; 1.0063x over previous
//
#include <hip/hip_runtime.h>
#include <hip/hip_bf16.h>

#define Bn 16384
#define Dn 512
#define Hn 1024
#define On 512
#define En 8
#define MTILES 264            // ceil((32768 + 8*127)/128)
#define MAXP (MTILES * 128)   // 33792 padded token-expert pairs
#define NPAIR (Bn * 2)        // 32768
#define SBLK 64               // scan blocks (512 thr each)

typedef __attribute__((ext_vector_type(8))) short bf16x8;
typedef __attribute__((ext_vector_type(4))) float f32x4;

typedef __attribute__((address_space(3))) unsigned lds_u;
typedef __attribute__((address_space(1))) const unsigned glb_u;
// async global->LDS, 16B per lane; LDS dest = wave-uniform base + lane*16
__device__ __forceinline__ void cp16(const unsigned short* g, void* l) {
  __builtin_amdgcn_global_load_lds((glb_u*)g, (lds_u*)l, 16, 0, 0);
}

// bijective XCD-aware remap (T1); valid since our grids are multiples of 8
__device__ __forceinline__ int xcd_swz(int orig, int nwg) {
  int q = nwg >> 3;
  return (orig & 7) * q + (orig >> 3);
}

__device__ __forceinline__ unsigned short f2bf(float f) {
  union { float f; unsigned u; } v; v.f = f;
  unsigned r = v.u + 0x7FFFu + ((v.u >> 16) & 1u);   // RNE
  return (unsigned short)(r >> 16);
}
__device__ __forceinline__ float bf2f(short s) {
  union { unsigned u; float f; } v; v.u = ((unsigned)(unsigned short)s) << 16; return v.f;
}

// ======== prep (fused): gate (bid<4096) + weight transpose (bid>=4096) ========
// gate: fp64 dot (exact top-k ordering) + register-only fp32 tail, no atomics;
//       also converts its x row to bf16. Reduction = butterfly-TRANSPOSE
//       (packed sends: 7 dp shuffles in-group + 3 cross-group + 8 gather = 18 dp,
//       vs 48 dp for the naive 6x8 butterfly).
__global__ __launch_bounds__(256) void k_prep(const float* __restrict__ x,
    const float* __restrict__ gw, const float* __restrict__ gb,
    const float* __restrict__ w1, const float* __restrict__ w2,
    unsigned short* __restrict__ xb,
    unsigned short* __restrict__ w1t, unsigned short* __restrict__ w2t,
    float* __restrict__ raw_out, float* __restrict__ idx_out,
    int* __restrict__ top_e, float* __restrict__ top_w,
    float* __restrict__ entp) {
  __shared__ float tile[32][33];
  __shared__ float ent_s[4];
  int bid = blockIdx.x;
  if (bid >= 4096) {
    // ---------------- transpose branch ----------------
    int tb = bid - 4096;
    const float* s; unsigned short* d; int R, C, c0, r0, ez;
    if (tb < 4096) {
      ez = tb >> 9; int tl = tb & 511;
      R = Dn; C = Hn; c0 = (tl & 31) * 32; r0 = (tl >> 5) * 32;
      s = w1; d = w1t;
    } else {
      ez = (tb - 4096) >> 9; int tl = tb & 511;
      R = Hn; C = On; c0 = (tl & 15) * 32; r0 = (tl >> 4) * 32;
      s = w2; d = w2t;
    }
    const float* se = s + (size_t)ez * R * C;
    unsigned short* de = d + (size_t)ez * R * C;
    int tx = threadIdx.x & 31, ty = threadIdx.x >> 5;
#pragma unroll
    for (int i = 0; i < 32; i += 8)
      tile[ty + i][tx] = se[(size_t)(r0 + ty + i) * C + (c0 + tx)];
    __syncthreads();
#pragma unroll
    for (int i = 0; i < 32; i += 8)
      de[(size_t)(c0 + ty + i) * R + (r0 + tx)] = f2bf(tile[tx][ty + i]);
    return;
  }
  // ---------------- gate branch ----------------
  int lane = threadIdx.x & 63, wid = threadIdx.x >> 6;
  int t = bid * 4 + wid;
  const float* xr = x + (size_t)t * Dn + lane * 8;
  f32x4 x0 = *(const f32x4*)xr;
  f32x4 x1 = *(const f32x4*)(xr + 4);
  // fused x -> bf16 (16 B per lane, full row per wave)
  ushort4 cv0, cv1;
  cv0.x = f2bf(x0[0]); cv0.y = f2bf(x0[1]); cv0.z = f2bf(x0[2]); cv0.w = f2bf(x0[3]);
  cv1.x = f2bf(x1[0]); cv1.y = f2bf(x1[1]); cv1.z = f2bf(x1[2]); cv1.w = f2bf(x1[3]);
  unsigned short* xbr = xb + (size_t)t * Dn + lane * 8;
  *(ushort4*)xbr = cv0;
  *(ushort4*)(xbr + 4) = cv1;
  double s0 = 0, s1 = 0, s2 = 0, s3 = 0, s4 = 0, s5 = 0, s6 = 0, s7 = 0;
#pragma unroll
  for (int j = 0; j < 8; ++j) {
    float xv = (j < 4) ? x0[j] : x1[j - 4];
    const float* wr = gw + (size_t)(lane * 8 + j) * 8;
    f32x4 w0 = *(const f32x4*)wr;
    f32x4 w1v = *(const f32x4*)(wr + 4);
    double xd = (double)xv;
    s0 += xd * (double)w0[0]; s1 += xd * (double)w0[1];
    s2 += xd * (double)w0[2]; s3 += xd * (double)w0[3];
    s4 += xd * (double)w1v[0]; s5 += xd * (double)w1v[1];
    s6 += xd * (double)w1v[2]; s7 += xd * (double)w1v[3];
  }
  // --- butterfly-transpose reduce: lane l ends with expert (l&7)'s full sum ---
  // round 0 (bit 0): keep e with e.bit0 == lane.bit0, send the other 4 (packed)
  {
    bool b = lane & 1;
    double t0 = b ? s0 : s1, t1 = b ? s2 : s3, t2 = b ? s4 : s5, t3 = b ? s6 : s7;
    double k0 = b ? s1 : s0, k1 = b ? s3 : s2, k2 = b ? s5 : s4, k3 = b ? s7 : s6;
    k0 += __shfl_xor(t0, 1, 64);
    k1 += __shfl_xor(t1, 1, 64);
    k2 += __shfl_xor(t2, 1, 64);
    k3 += __shfl_xor(t3, 1, 64);
    // k_i holds e = (i<<1)|lane.bit0
    // round 1 (bit 1): e.bit1 = i.bit0; keep i.bit0 == lane.bit1
    bool c = lane & 2;
    double u0 = c ? k0 : k1, u1 = c ? k2 : k3;
    double m0 = c ? k1 : k0, m1 = c ? k3 : k2;
    m0 += __shfl_xor(u0, 2, 64);
    m1 += __shfl_xor(u1, 2, 64);
    // m_j holds e = (j<<2)|(lane.bit1<<1)|lane.bit0
    // round 2 (bit 2): keep j == lane.bit2
    bool d = lane & 4;
    double w0v = d ? m0 : m1;
    double z = d ? m1 : m0;
    z += __shfl_xor(w0v, 4, 64);
    // z = group-of-8 sum for expert (lane&7); reduce across the 8 groups
    z += __shfl_xor(z, 8, 64);
    z += __shfl_xor(z, 16, 64);
    z += __shfl_xor(z, 32, 64);
    s0 = z;   // reuse s0 as the final per-lane expert sum
  }
  // gather all 8 expert logits into every lane (lane e holds expert e)
  double raw[8];
#pragma unroll
  for (int e = 0; e < 8; ++e) raw[e] = __shfl(s0, e, 64) + (double)gb[e];
  // branchless top-2 (fp64 compares, strict > : ties -> lower index, matches lax.top_k)
  double v0 = raw[0], v1 = -1e300;
  int i0 = 0, i1 = 0;
#pragma unroll
  for (int e = 1; e < 8; ++e) {
    bool g0 = raw[e] > v0;
    bool g1 = raw[e] > v1;
    double nv1 = g0 ? v0 : (g1 ? raw[e] : v1);
    int    ni1 = g0 ? i0 : (g1 ? e      : i1);
    v1 = nv1; i1 = ni1;
    v0 = g0 ? raw[e] : v0;
    i0 = g0 ? e      : i0;
  }
  float pf[8], s = 0.f;
#pragma unroll
  for (int e = 0; e < 8; ++e) { pf[e] = __expf((float)(raw[e] - v0)); s += pf[e]; }
  float inv = 1.f / s, ent = 0.f;
#pragma unroll
  for (int e = 0; e < 8; ++e) { float p = pf[e] * inv; ent -= p * __logf(p + 1e-9f); }
  float p0 = inv;
  float p1 = __expf((float)(v1 - v0)) * inv;
  float cw0 = 1.f / (1.f + __expf(p1 - p0));       // softmax over top-2 PROBS
  if (lane == 0) {
    f32x4 ra, rb;
    ra[0] = (float)raw[0]; ra[1] = (float)raw[1]; ra[2] = (float)raw[2]; ra[3] = (float)raw[3];
    rb[0] = (float)raw[4]; rb[1] = (float)raw[5]; rb[2] = (float)raw[6]; rb[3] = (float)raw[7];
    *(f32x4*)(raw_out + (size_t)t * 8) = ra;
    *(f32x4*)(raw_out + (size_t)t * 8 + 4) = rb;
    idx_out[t * 2 + 0] = (float)i0; idx_out[t * 2 + 1] = (float)i1;
    top_e[t * 2 + 0] = i0; top_e[t * 2 + 1] = i1;
    top_w[t * 2 + 0] = cw0; top_w[t * 2 + 1] = 1.f - cw0;
    ent_s[wid] = ent;
  }
  __syncthreads();
  if (threadIdx.x == 0) entp[bid] = (ent_s[0] + ent_s[1]) + (ent_s[2] + ent_s[3]);
}

// ---------- atomic-free routing: ballot histogram -> scan -> ranked scatter ----------
__global__ __launch_bounds__(512) void k_hist(const int* __restrict__ top_e,
                                              int* __restrict__ bc) {
  int p = blockIdx.x * 512 + threadIdx.x;
  int lane = threadIdx.x & 63, w = threadIdx.x >> 6;
  int e = top_e[p];
  __shared__ int wc[8][8];
#pragma unroll
  for (int v = 0; v < 8; ++v) {
    unsigned long long m = __ballot(e == v);
    if (lane == 0) wc[w][v] = __popcll(m);
  }
  __syncthreads();
  if (threadIdx.x < 8) {
    int sum = 0;
#pragma unroll
    for (int w2 = 0; w2 < 8; ++w2) sum += wc[w2][threadIdx.x];
    bc[blockIdx.x * 8 + threadIdx.x] = sum;
  }
}

// 1 block, 512 threads: wave = expert, lane = scan-block; also finalizes entropy.
// tok padding is handled by hipMemsetAsync(tok, 0) at launch (token 0: harmless compute,
// padded rows are never read by k_combine).
__global__ __launch_bounds__(512) void k_offsets(const int* __restrict__ bc,
    int* __restrict__ ob, int* __restrict__ tile_expert,
    const float* __restrict__ entp, float* __restrict__ ent_out) {
  int lane = threadIdx.x & 63;     // scan-block b
  int e = threadIdx.x >> 6;        // expert
  int v = bc[lane * 8 + e];
  int sum = v;
#pragma unroll
  for (int off = 1; off < 64; off <<= 1) {
    int o = __shfl_up(sum, off, 64);
    if (lane >= off) sum += o;
  }
  int excl = sum - v;
  __shared__ int tot8[8], po[9];
  __shared__ float es[512];
  // entropy finalize (independent of the scan)
  float ev = 0.f;
  for (int i = threadIdx.x; i < 4096; i += 512) ev += entp[i];
  es[threadIdx.x] = ev;
  if (lane == 63) tot8[e] = sum;
  __syncthreads();
  for (int o = 256; o; o >>= 1) {
    if (threadIdx.x < o) es[threadIdx.x] += es[threadIdx.x + o];
    __syncthreads();
  }
  if (threadIdx.x == 0) ent_out[0] = es[0] / (float)Bn;
  int seg = 0;
#pragma unroll
  for (int e2 = 0; e2 < 8; ++e2) {
    int padded = ((tot8[e2] + 127) >> 7) << 7;
    seg += (e2 < e) ? padded : 0;
  }
  ob[lane * 8 + e] = seg + excl;
  if (lane == 0) po[e] = seg;
  if (threadIdx.x == 511) po[8] = seg + (((tot8[7] + 127) >> 7) << 7);
  __syncthreads();
  for (int i = threadIdx.x; i < MTILES; i += 512) {
    int base = i * 128, ee = -1;
#pragma unroll
    for (int j = 0; j < 8; ++j) if (base >= po[j] && base < po[j + 1]) ee = j;
    tile_expert[i] = ee;
  }
}

__global__ __launch_bounds__(512) void k_scatter2(const int* __restrict__ top_e,
    const float* __restrict__ top_w, const int* __restrict__ ob,
    int* __restrict__ tok, int* __restrict__ pos_tk) {
  int p = blockIdx.x * 512 + threadIdx.x;
  int lane = threadIdx.x & 63, w = threadIdx.x >> 6;
  int e = top_e[p];
  __shared__ int wc[8][8];
  unsigned long long lt = (1ULL << lane) - 1;
  int rank = 0;
#pragma unroll
  for (int v = 0; v < 8; ++v) {
    unsigned long long m = __ballot(e == v);
    if (lane == 0) wc[w][v] = __popcll(m);
    if (e == v) rank = __popcll(m & lt);
  }
  __syncthreads();
  int wpre = 0;
#pragma unroll
  for (int w2 = 0; w2 < 8; ++w2) wpre += (w2 < w) ? wc[w2][e] : 0;   // LDS runtime idx ok
  int pos = ob[blockIdx.x * 8 + e] + wpre + rank;
  tok[pos] = p >> 1;
  pos_tk[p] = pos;
}

// ============ GEMM1: h[pair][H] = relu(x[tok]·w1[e] + b1[e]), 128x128 tile ============
// R9-proven: single-buffer 2-barrier K-loop, 4 waves, XCD swizzle, global_load_lds(16B)
__global__ __launch_bounds__(256) void k_gemm1(const unsigned short* __restrict__ xb,
    const unsigned short* __restrict__ w1t, const float* __restrict__ b1,
    const int* __restrict__ tok, const int* __restrict__ tile_expert,
    unsigned short* __restrict__ h) {
  const int wg = xcd_swz(blockIdx.x, MTILES * (Hn / 128));
  const int mt = wg >> 3, nb = wg & 7;
  int e = tile_expert[mt];
  if (e < 0) return;
  const int m0 = mt * 128, n0 = nb * 128;
  __shared__ char As[16384];
  __shared__ char Bs[16384];
  const int tid = threadIdx.x, lane = tid & 63, wv = tid >> 6;
  const int wm = wv >> 1, wn = wv & 1;
  const int rA = tid >> 3;
  const int c8 = ((tid & 7) ^ ((tid >> 3) & 7)) * 8;
  int trow[4];
#pragma unroll
  for (int i = 0; i < 4; ++i) trow[i] = tok[m0 + i * 32 + rA];
  const unsigned short* w1e = w1t + (size_t)e * Hn * Dn;
  f32x4 acc[4][4];
#pragma unroll
  for (int m = 0; m < 4; ++m)
#pragma unroll
    for (int n = 0; n < 4; ++n) acc[m][n] = (f32x4){0.f, 0.f, 0.f, 0.f};

  for (int kt = 0; kt < Dn / 64; ++kt) {
    const int k0 = kt * 64;
    if (kt) __syncthreads();
#pragma unroll
    for (int i = 0; i < 4; ++i)
      cp16(xb + (size_t)trow[i] * Dn + k0 + c8, As + i * 4096 + wv * 1024);
#pragma unroll
    for (int i = 0; i < 4; ++i)
      cp16(w1e + (size_t)(n0 + i * 32 + rA) * Dn + k0 + c8, Bs + i * 4096 + wv * 1024);
    __syncthreads();
#pragma unroll
    for (int kk = 0; kk < 2; ++kk) {
      const int bc = kk * 64 + (lane >> 4) * 16;
      bf16x8 a[4], b[4];
#pragma unroll
      for (int m = 0; m < 4; ++m) {
        int r = wm * 64 + m * 16 + (lane & 15);
        a[m] = *(const bf16x8*)(As + r * 128 + (bc ^ ((r & 7) << 4)));
      }
#pragma unroll
      for (int n = 0; n < 4; ++n) {
        int r = wn * 64 + n * 16 + (lane & 15);
        b[n] = *(const bf16x8*)(Bs + r * 128 + (bc ^ ((r & 7) << 4)));
      }
#pragma unroll
      for (int m = 0; m < 4; ++m)
#pragma unroll
        for (int n = 0; n < 4; ++n)
          acc[m][n] = __builtin_amdgcn_mfma_f32_16x16x32_bf16(a[m], b[n], acc[m][n], 0, 0, 0);
    }
  }
#pragma unroll
  for (int n = 0; n < 4; ++n) {
    int gcol = n0 + wn * 64 + n * 16 + (lane & 15);
    float bias = b1[e * Hn + gcol];
#pragma unroll
    for (int m = 0; m < 4; ++m) {
      int grow = m0 + wm * 64 + m * 16 + ((lane >> 4) << 2);
#pragma unroll
      for (int r = 0; r < 4; ++r) {
        float v = fmaxf(acc[m][n][r] + bias, 0.f);
        h[(size_t)(grow + r) * Hn + gcol] = f2bf(v);
      }
    }
  }
}

// ============ GEMM2: y[pair][O] = h·w2[e] + b2[e] (bf16), 128x128 tile ============
__global__ __launch_bounds__(256) void k_gemm2(const unsigned short* __restrict__ h,
    const unsigned short* __restrict__ w2t, const float* __restrict__ b2,
    const int* __restrict__ tile_expert, unsigned short* __restrict__ y) {
  const int wg = xcd_swz(blockIdx.x, MTILES * (On / 128));
  const int mt = wg >> 2, nb = wg & 3;
  int e = tile_expert[mt];
  if (e < 0) return;
  const int m0 = mt * 128, n0 = nb * 128;
  __shared__ char As[16384];
  __shared__ char Bs[16384];
  const int tid = threadIdx.x, lane = tid & 63, wv = tid >> 6;
  const int wm = wv >> 1, wn = wv & 1;
  const int rA = tid >> 3;
  const int c8 = ((tid & 7) ^ ((tid >> 3) & 7)) * 8;
  const unsigned short* w2e = w2t + (size_t)e * On * Hn;
  f32x4 acc[4][4];
#pragma unroll
  for (int m = 0; m < 4; ++m)
#pragma unroll
    for (int n = 0; n < 4; ++n) acc[m][n] = (f32x4){0.f, 0.f, 0.f, 0.f};

  for (int kt = 0; kt < Hn / 64; ++kt) {
    const int k0 = kt * 64;
    if (kt) __syncthreads();
#pragma unroll
    for (int i = 0; i < 4; ++i)
      cp16(h + (size_t)(m0 + i * 32 + rA) * Hn + k0 + c8, As + i * 4096 + wv * 1024);
#pragma unroll
    for (int i = 0; i < 4; ++i)
      cp16(w2e + (size_t)(n0 + i * 32 + rA) * Hn + k0 + c8, Bs + i * 4096 + wv * 1024);
    __syncthreads();
#pragma unroll
    for (int kk = 0; kk < 2; ++kk) {
      const int bc = kk * 64 + (lane >> 4) * 16;
      bf16x8 a[4], b[4];
#pragma unroll
      for (int m = 0; m < 4; ++m) {
        int r = wm * 64 + m * 16 + (lane & 15);
        a[m] = *(const bf16x8*)(As + r * 128 + (bc ^ ((r & 7) << 4)));
      }
#pragma unroll
      for (int n = 0; n < 4; ++n) {
        int r = wn * 64 + n * 16 + (lane & 15);
        b[n] = *(const bf16x8*)(Bs + r * 128 + (bc ^ ((r & 7) << 4)));
      }
#pragma unroll
      for (int m = 0; m < 4; ++m)
#pragma unroll
        for (int n = 0; n < 4; ++n)
          acc[m][n] = __builtin_amdgcn_mfma_f32_16x16x32_bf16(a[m], b[n], acc[m][n], 0, 0, 0);
    }
  }
#pragma unroll
  for (int n = 0; n < 4; ++n) {
    int gcol = n0 + wn * 64 + n * 16 + (lane & 15);
    float bias = b2[e * On + gcol];
#pragma unroll
    for (int m = 0; m < 4; ++m) {
      int grow = m0 + wm * 64 + m * 16 + ((lane >> 4) << 2);
#pragma unroll
      for (int r = 0; r < 4; ++r)
        y[(size_t)(grow + r) * On + gcol] = f2bf(acc[m][n][r] + bias);
    }
  }
}

// ---------------- combine: out[t] = w0*y[p0] + w1*y[p1] ----------------
__global__ __launch_bounds__(256) void k_combine(const unsigned short* __restrict__ y,
    const int* __restrict__ pos_tk, const float* __restrict__ top_w,
    float* __restrict__ out) {
  int wid = threadIdx.x >> 6, lane = threadIdx.x & 63;
  int t = blockIdx.x * 4 + wid;
  int p0 = pos_tk[t * 2], p1 = pos_tk[t * 2 + 1];
  float w0 = top_w[t * 2], w1 = top_w[t * 2 + 1];
  bf16x8 a = *(const bf16x8*)(y + (size_t)p0 * On + lane * 8);
  bf16x8 b = *(const bf16x8*)(y + (size_t)p1 * On + lane * 8);
  f32x4 o0, o1;
#pragma unroll
  for (int j = 0; j < 4; ++j) {
    o0[j] = w0 * bf2f(a[j]) + w1 * bf2f(b[j]);
    o1[j] = w0 * bf2f(a[j + 4]) + w1 * bf2f(b[j + 4]);
  }
  float* op = out + (size_t)t * On + lane * 8;
  *(f32x4*)op = o0;
  *(f32x4*)(op + 4) = o1;
}

extern "C" void kernel_launch(void* const* d_in, const int* in_sizes, int n_in,
                              void* d_out, int out_size, void* d_ws, size_t ws_size,
                              hipStream_t stream) {
  const float* x  = (const float*)d_in[0];
  const float* gw = (const float*)d_in[1];
  const float* gb = (const float*)d_in[2];
  const float* w1 = (const float*)d_in[3];
  const float* b1 = (const float*)d_in[4];
  const float* w2 = (const float*)d_in[5];
  const float* b2 = (const float*)d_in[6];
  float* out     = (float*)d_out;
  float* raw_out = out + (size_t)Bn * On;
  float* idx_out = raw_out + (size_t)Bn * En;
  float* ent_out = idx_out + (size_t)Bn * 2;

  char* ws = (char*)d_ws;
  size_t off = 0;
  auto alloc = [&](size_t bytes) { char* p = ws + off; off += (bytes + 255) & ~(size_t)255; return p; };
  unsigned short* xb   = (unsigned short*)alloc((size_t)Bn * Dn * 2);
  unsigned short* w1t  = (unsigned short*)alloc((size_t)En * Hn * Dn * 2);
  unsigned short* w2t  = (unsigned short*)alloc((size_t)En * On * Hn * 2);
  unsigned short* hbuf = (unsigned short*)alloc((size_t)MAXP * Hn * 2);
  unsigned short* ybuf = (unsigned short*)alloc((size_t)MAXP * On * 2);
  int*   tok    = (int*)alloc((size_t)MAXP * 4);
  int*   pos_tk = (int*)alloc((size_t)NPAIR * 4);
  int*   top_e  = (int*)alloc((size_t)NPAIR * 4);
  float* top_w  = (float*)alloc((size_t)NPAIR * 4);
  int*   bc     = (int*)alloc(SBLK * 8 * 4);
  int*   ob     = (int*)alloc(SBLK * 8 * 4);
  int*   tile_expert = (int*)alloc(MTILES * 4);
  float* entp   = (float*)alloc(4096 * 4);

  // padding rows of tok -> token 0 (harmless: padded h/y rows are never read)
  hipMemsetAsync(tok, 0, (size_t)MAXP * 4, stream);

  k_prep<<<12288, 256, 0, stream>>>(x, gw, gb, w1, w2, xb, w1t, w2t,
                                    raw_out, idx_out, top_e, top_w, entp);
  k_hist<<<SBLK, 512, 0, stream>>>(top_e, bc);
  k_offsets<<<1, 512, 0, stream>>>(bc, ob, tile_expert, entp, ent_out);
  k_scatter2<<<SBLK, 512, 0, stream>>>(top_e, top_w, ob, tok, pos_tk);
  k_gemm1<<<MTILES * (Hn / 128), 256, 0, stream>>>(xb, w1t, b1, tok, tile_expert, hbuf);
  k_gemm2<<<MTILES * (On / 128), 256, 0, stream>>>(hbuf, w2t, b2, tile_expert, ybuf);
  k_combine<<<Bn / 4, 256, 0, stream>>>(ybuf, pos_tk, top_w, out);
}

// Round 17
// 143.603 us; speedup vs baseline: 1.5030x; 1.0867x over previous
//
#include <hip/hip_runtime.h>
#include <hip/hip_bf16.h>

#define Bn 16384
#define Dn 512
#define Hn 1024
#define On 512
#define En 8
#define MTILES 264            // ceil((32768 + 8*127)/128)
#define MAXP (MTILES * 128)   // 33792 padded token-expert pairs
#define NPAIR (Bn * 2)        // 32768
#define SBLK 64               // scan blocks (512 thr each)

typedef __attribute__((ext_vector_type(8))) short bf16x8;
typedef __attribute__((ext_vector_type(4))) float f32x4;

typedef __attribute__((address_space(3))) unsigned lds_u;
typedef __attribute__((address_space(1))) const unsigned glb_u;
// async global->LDS, 16B per lane; LDS dest = wave-uniform base + lane*16
__device__ __forceinline__ void cp16(const unsigned short* g, void* l) {
  __builtin_amdgcn_global_load_lds((glb_u*)g, (lds_u*)l, 16, 0, 0);
}

// bijective XCD-aware remap (T1); valid since our grids are multiples of 8
__device__ __forceinline__ int xcd_swz(int orig, int nwg) {
  int q = nwg >> 3;
  return (orig & 7) * q + (orig >> 3);
}

__device__ __forceinline__ unsigned short f2bf(float f) {
  union { float f; unsigned u; } v; v.f = f;
  unsigned r = v.u + 0x7FFFu + ((v.u >> 16) & 1u);   // RNE
  return (unsigned short)(r >> 16);
}
__device__ __forceinline__ float bf2f(short s) {
  union { unsigned u; float f; } v; v.u = ((unsigned)(unsigned short)s) << 16; return v.f;
}

// ======== prep (fused+interleaved): gate (bid%3==0) + weight transpose (rest) ========
// Interleaving makes gate (VALU/latency-heavy) and transpose (BW-heavy) co-resident
// on every CU instead of dispatching serially (R16 lesson: bid-ordered phases
// serialize). Gate lane->k ownership is k = lane + 64j so gw loads are 32B
// lane-stride (contiguous 2KB/instr) instead of 256B stride (16KB span/instr).
__global__ __launch_bounds__(256) void k_prep(const float* __restrict__ x,
    const float* __restrict__ gw, const float* __restrict__ gb,
    const float* __restrict__ w1, const float* __restrict__ w2,
    unsigned short* __restrict__ xb,
    unsigned short* __restrict__ w1t, unsigned short* __restrict__ w2t,
    float* __restrict__ raw_out, float* __restrict__ idx_out,
    int* __restrict__ top_e, float* __restrict__ top_w,
    float* __restrict__ entp) {
  __shared__ float tile[32][33];
  __shared__ float ent_s[4];
  int bid = blockIdx.x;
  if (bid % 3 != 0) {
    // ---------------- transpose branch (tb in [0, 8192)) ----------------
    int k3 = bid / 3;
    int tb = (bid % 3 == 1) ? (2 * k3) : (2 * k3 + 1);
    const float* s; unsigned short* d; int R, C, c0, r0, ez;
    if (tb < 4096) {
      ez = tb >> 9; int tl = tb & 511;
      R = Dn; C = Hn; c0 = (tl & 31) * 32; r0 = (tl >> 5) * 32;
      s = w1; d = w1t;
    } else {
      ez = (tb - 4096) >> 9; int tl = tb & 511;
      R = Hn; C = On; c0 = (tl & 15) * 32; r0 = (tl >> 4) * 32;
      s = w2; d = w2t;
    }
    const float* se = s + (size_t)ez * R * C;
    unsigned short* de = d + (size_t)ez * R * C;
    int tx = threadIdx.x & 31, ty = threadIdx.x >> 5;
#pragma unroll
    for (int i = 0; i < 32; i += 8)
      tile[ty + i][tx] = se[(size_t)(r0 + ty + i) * C + (c0 + tx)];
    __syncthreads();
#pragma unroll
    for (int i = 0; i < 32; i += 8)
      de[(size_t)(c0 + ty + i) * R + (r0 + tx)] = f2bf(tile[tx][ty + i]);
    return;
  }
  // ---------------- gate branch (g in [0, 4096)) ----------------
  int g = bid / 3;
  int lane = threadIdx.x & 63, wid = threadIdx.x >> 6;
  int t = g * 4 + wid;
  const float* xrow = x + (size_t)t * Dn;
  float xv[8];
#pragma unroll
  for (int j = 0; j < 8; ++j) xv[j] = xrow[lane + 64 * j];   // 256B/instr coalesced
  unsigned short* xbr = xb + (size_t)t * Dn;
#pragma unroll
  for (int j = 0; j < 8; ++j) xbr[lane + 64 * j] = f2bf(xv[j]);
  double s0 = 0, s1 = 0, s2 = 0, s3 = 0, s4 = 0, s5 = 0, s6 = 0, s7 = 0;
#pragma unroll
  for (int j = 0; j < 8; ++j) {
    const float* wr = gw + (size_t)(lane + 64 * j) * 8;      // 32B lane-stride
    f32x4 w0 = *(const f32x4*)wr;
    f32x4 w1v = *(const f32x4*)(wr + 4);
    double xd = (double)xv[j];
    s0 += xd * (double)w0[0]; s1 += xd * (double)w0[1];
    s2 += xd * (double)w0[2]; s3 += xd * (double)w0[3];
    s4 += xd * (double)w1v[0]; s5 += xd * (double)w1v[1];
    s6 += xd * (double)w1v[2]; s7 += xd * (double)w1v[3];
  }
  // --- butterfly-transpose reduce: lane l ends with expert (l&7)'s full sum ---
  {
    bool b = lane & 1;
    double t0 = b ? s0 : s1, t1 = b ? s2 : s3, t2 = b ? s4 : s5, t3 = b ? s6 : s7;
    double k0 = b ? s1 : s0, k1 = b ? s3 : s2, k2 = b ? s5 : s4, k3 = b ? s7 : s6;
    k0 += __shfl_xor(t0, 1, 64);
    k1 += __shfl_xor(t1, 1, 64);
    k2 += __shfl_xor(t2, 1, 64);
    k3 += __shfl_xor(t3, 1, 64);
    bool c = lane & 2;
    double u0 = c ? k0 : k1, u1 = c ? k2 : k3;
    double m0 = c ? k1 : k0, m1 = c ? k3 : k2;
    m0 += __shfl_xor(u0, 2, 64);
    m1 += __shfl_xor(u1, 2, 64);
    bool d = lane & 4;
    double w0v = d ? m0 : m1;
    double z = d ? m1 : m0;
    z += __shfl_xor(w0v, 4, 64);
    z += __shfl_xor(z, 8, 64);
    z += __shfl_xor(z, 16, 64);
    z += __shfl_xor(z, 32, 64);
    s0 = z;   // final per-lane expert sum (expert = lane&7)
  }
  double raw[8];
#pragma unroll
  for (int e = 0; e < 8; ++e) raw[e] = __shfl(s0, e, 64) + (double)gb[e];
  // branchless top-2 (fp64 compares, strict > : ties -> lower index, matches lax.top_k)
  double v0 = raw[0], v1 = -1e300;
  int i0 = 0, i1 = 0;
#pragma unroll
  for (int e = 1; e < 8; ++e) {
    bool g0 = raw[e] > v0;
    bool g1 = raw[e] > v1;
    double nv1 = g0 ? v0 : (g1 ? raw[e] : v1);
    int    ni1 = g0 ? i0 : (g1 ? e      : i1);
    v1 = nv1; i1 = ni1;
    v0 = g0 ? raw[e] : v0;
    i0 = g0 ? e      : i0;
  }
  float pf[8], s = 0.f;
#pragma unroll
  for (int e = 0; e < 8; ++e) { pf[e] = __expf((float)(raw[e] - v0)); s += pf[e]; }
  float inv = 1.f / s, ent = 0.f;
#pragma unroll
  for (int e = 0; e < 8; ++e) { float p = pf[e] * inv; ent -= p * __logf(p + 1e-9f); }
  float p0 = inv;
  float p1 = __expf((float)(v1 - v0)) * inv;
  float cw0 = 1.f / (1.f + __expf(p1 - p0));       // softmax over top-2 PROBS
  if (lane == 0) {
    f32x4 ra, rb;
    ra[0] = (float)raw[0]; ra[1] = (float)raw[1]; ra[2] = (float)raw[2]; ra[3] = (float)raw[3];
    rb[0] = (float)raw[4]; rb[1] = (float)raw[5]; rb[2] = (float)raw[6]; rb[3] = (float)raw[7];
    *(f32x4*)(raw_out + (size_t)t * 8) = ra;
    *(f32x4*)(raw_out + (size_t)t * 8 + 4) = rb;
    idx_out[t * 2 + 0] = (float)i0; idx_out[t * 2 + 1] = (float)i1;
    top_e[t * 2 + 0] = i0; top_e[t * 2 + 1] = i1;
    top_w[t * 2 + 0] = cw0; top_w[t * 2 + 1] = 1.f - cw0;
    ent_s[wid] = ent;
  }
  __syncthreads();
  if (threadIdx.x == 0) entp[g] = (ent_s[0] + ent_s[1]) + (ent_s[2] + ent_s[3]);
}

// ---------- atomic-free routing: ballot histogram -> scan -> ranked scatter ----------
__global__ __launch_bounds__(512) void k_hist(const int* __restrict__ top_e,
                                              int* __restrict__ bc) {
  int p = blockIdx.x * 512 + threadIdx.x;
  int lane = threadIdx.x & 63, w = threadIdx.x >> 6;
  int e = top_e[p];
  __shared__ int wc[8][8];
#pragma unroll
  for (int v = 0; v < 8; ++v) {
    unsigned long long m = __ballot(e == v);
    if (lane == 0) wc[w][v] = __popcll(m);
  }
  __syncthreads();
  if (threadIdx.x < 8) {
    int sum = 0;
#pragma unroll
    for (int w2 = 0; w2 < 8; ++w2) sum += wc[w2][threadIdx.x];
    bc[blockIdx.x * 8 + threadIdx.x] = sum;
  }
}

// 1 block, 512 threads: wave = expert, lane = scan-block; also finalizes entropy.
// tok padding is handled by hipMemsetAsync(tok, 0) at launch (token 0: harmless compute,
// padded rows are never read by k_combine).
__global__ __launch_bounds__(512) void k_offsets(const int* __restrict__ bc,
    int* __restrict__ ob, int* __restrict__ tile_expert,
    const float* __restrict__ entp, float* __restrict__ ent_out) {
  int lane = threadIdx.x & 63;     // scan-block b
  int e = threadIdx.x >> 6;        // expert
  int v = bc[lane * 8 + e];
  int sum = v;
#pragma unroll
  for (int off = 1; off < 64; off <<= 1) {
    int o = __shfl_up(sum, off, 64);
    if (lane >= off) sum += o;
  }
  int excl = sum - v;
  __shared__ int tot8[8], po[9];
  __shared__ float es[512];
  // entropy finalize (independent of the scan)
  float ev = 0.f;
  for (int i = threadIdx.x; i < 4096; i += 512) ev += entp[i];
  es[threadIdx.x] = ev;
  if (lane == 63) tot8[e] = sum;
  __syncthreads();
  for (int o = 256; o; o >>= 1) {
    if (threadIdx.x < o) es[threadIdx.x] += es[threadIdx.x + o];
    __syncthreads();
  }
  if (threadIdx.x == 0) ent_out[0] = es[0] / (float)Bn;
  int seg = 0;
#pragma unroll
  for (int e2 = 0; e2 < 8; ++e2) {
    int padded = ((tot8[e2] + 127) >> 7) << 7;
    seg += (e2 < e) ? padded : 0;
  }
  ob[lane * 8 + e] = seg + excl;
  if (lane == 0) po[e] = seg;
  if (threadIdx.x == 511) po[8] = seg + (((tot8[7] + 127) >> 7) << 7);
  __syncthreads();
  for (int i = threadIdx.x; i < MTILES; i += 512) {
    int base = i * 128, ee = -1;
#pragma unroll
    for (int j = 0; j < 8; ++j) if (base >= po[j] && base < po[j + 1]) ee = j;
    tile_expert[i] = ee;
  }
}

__global__ __launch_bounds__(512) void k_scatter2(const int* __restrict__ top_e,
    const float* __restrict__ top_w, const int* __restrict__ ob,
    int* __restrict__ tok, int* __restrict__ pos_tk) {
  int p = blockIdx.x * 512 + threadIdx.x;
  int lane = threadIdx.x & 63, w = threadIdx.x >> 6;
  int e = top_e[p];
  __shared__ int wc[8][8];
  unsigned long long lt = (1ULL << lane) - 1;
  int rank = 0;
#pragma unroll
  for (int v = 0; v < 8; ++v) {
    unsigned long long m = __ballot(e == v);
    if (lane == 0) wc[w][v] = __popcll(m);
    if (e == v) rank = __popcll(m & lt);
  }
  __syncthreads();
  int wpre = 0;
#pragma unroll
  for (int w2 = 0; w2 < 8; ++w2) wpre += (w2 < w) ? wc[w2][e] : 0;   // LDS runtime idx ok
  int pos = ob[blockIdx.x * 8 + e] + wpre + rank;
  tok[pos] = p >> 1;
  pos_tk[p] = pos;
}

// ============ GEMM1: h[pair][H] = relu(x[tok]·w1[e] + b1[e]), 128x128 tile ============
// R9-proven: single-buffer 2-barrier K-loop, 4 waves, XCD swizzle, global_load_lds(16B)
__global__ __launch_bounds__(256) void k_gemm1(const unsigned short* __restrict__ xb,
    const unsigned short* __restrict__ w1t, const float* __restrict__ b1,
    const int* __restrict__ tok, const int* __restrict__ tile_expert,
    unsigned short* __restrict__ h) {
  const int wg = xcd_swz(blockIdx.x, MTILES * (Hn / 128));
  const int mt = wg >> 3, nb = wg & 7;
  int e = tile_expert[mt];
  if (e < 0) return;
  const int m0 = mt * 128, n0 = nb * 128;
  __shared__ char As[16384];
  __shared__ char Bs[16384];
  const int tid = threadIdx.x, lane = tid & 63, wv = tid >> 6;
  const int wm = wv >> 1, wn = wv & 1;
  const int rA = tid >> 3;
  const int c8 = ((tid & 7) ^ ((tid >> 3) & 7)) * 8;
  int trow[4];
#pragma unroll
  for (int i = 0; i < 4; ++i) trow[i] = tok[m0 + i * 32 + rA];
  const unsigned short* w1e = w1t + (size_t)e * Hn * Dn;
  f32x4 acc[4][4];
#pragma unroll
  for (int m = 0; m < 4; ++m)
#pragma unroll
    for (int n = 0; n < 4; ++n) acc[m][n] = (f32x4){0.f, 0.f, 0.f, 0.f};

  for (int kt = 0; kt < Dn / 64; ++kt) {
    const int k0 = kt * 64;
    if (kt) __syncthreads();
#pragma unroll
    for (int i = 0; i < 4; ++i)
      cp16(xb + (size_t)trow[i] * Dn + k0 + c8, As + i * 4096 + wv * 1024);
#pragma unroll
    for (int i = 0; i < 4; ++i)
      cp16(w1e + (size_t)(n0 + i * 32 + rA) * Dn + k0 + c8, Bs + i * 4096 + wv * 1024);
    __syncthreads();
#pragma unroll
    for (int kk = 0; kk < 2; ++kk) {
      const int bc = kk * 64 + (lane >> 4) * 16;
      bf16x8 a[4], b[4];
#pragma unroll
      for (int m = 0; m < 4; ++m) {
        int r = wm * 64 + m * 16 + (lane & 15);
        a[m] = *(const bf16x8*)(As + r * 128 + (bc ^ ((r & 7) << 4)));
      }
#pragma unroll
      for (int n = 0; n < 4; ++n) {
        int r = wn * 64 + n * 16 + (lane & 15);
        b[n] = *(const bf16x8*)(Bs + r * 128 + (bc ^ ((r & 7) << 4)));
      }
#pragma unroll
      for (int m = 0; m < 4; ++m)
#pragma unroll
        for (int n = 0; n < 4; ++n)
          acc[m][n] = __builtin_amdgcn_mfma_f32_16x16x32_bf16(a[m], b[n], acc[m][n], 0, 0, 0);
    }
  }
#pragma unroll
  for (int n = 0; n < 4; ++n) {
    int gcol = n0 + wn * 64 + n * 16 + (lane & 15);
    float bias = b1[e * Hn + gcol];
#pragma unroll
    for (int m = 0; m < 4; ++m) {
      int grow = m0 + wm * 64 + m * 16 + ((lane >> 4) << 2);
#pragma unroll
      for (int r = 0; r < 4; ++r) {
        float v = fmaxf(acc[m][n][r] + bias, 0.f);
        h[(size_t)(grow + r) * Hn + gcol] = f2bf(v);
      }
    }
  }
}

// ============ GEMM2: y[pair][O] = h·w2[e] + b2[e] (bf16), 128x128 tile ============
__global__ __launch_bounds__(256) void k_gemm2(const unsigned short* __restrict__ h,
    const unsigned short* __restrict__ w2t, const float* __restrict__ b2,
    const int* __restrict__ tile_expert, unsigned short* __restrict__ y) {
  const int wg = xcd_swz(blockIdx.x, MTILES * (On / 128));
  const int mt = wg >> 2, nb = wg & 3;
  int e = tile_expert[mt];
  if (e < 0) return;
  const int m0 = mt * 128, n0 = nb * 128;
  __shared__ char As[16384];
  __shared__ char Bs[16384];
  const int tid = threadIdx.x, lane = tid & 63, wv = tid >> 6;
  const int wm = wv >> 1, wn = wv & 1;
  const int rA = tid >> 3;
  const int c8 = ((tid & 7) ^ ((tid >> 3) & 7)) * 8;
  const unsigned short* w2e = w2t + (size_t)e * On * Hn;
  f32x4 acc[4][4];
#pragma unroll
  for (int m = 0; m < 4; ++m)
#pragma unroll
    for (int n = 0; n < 4; ++n) acc[m][n] = (f32x4){0.f, 0.f, 0.f, 0.f};

  for (int kt = 0; kt < Hn / 64; ++kt) {
    const int k0 = kt * 64;
    if (kt) __syncthreads();
#pragma unroll
    for (int i = 0; i < 4; ++i)
      cp16(h + (size_t)(m0 + i * 32 + rA) * Hn + k0 + c8, As + i * 4096 + wv * 1024);
#pragma unroll
    for (int i = 0; i < 4; ++i)
      cp16(w2e + (size_t)(n0 + i * 32 + rA) * Hn + k0 + c8, Bs + i * 4096 + wv * 1024);
    __syncthreads();
#pragma unroll
    for (int kk = 0; kk < 2; ++kk) {
      const int bc = kk * 64 + (lane >> 4) * 16;
      bf16x8 a[4], b[4];
#pragma unroll
      for (int m = 0; m < 4; ++m) {
        int r = wm * 64 + m * 16 + (lane & 15);
        a[m] = *(const bf16x8*)(As + r * 128 + (bc ^ ((r & 7) << 4)));
      }
#pragma unroll
      for (int n = 0; n < 4; ++n) {
        int r = wn * 64 + n * 16 + (lane & 15);
        b[n] = *(const bf16x8*)(Bs + r * 128 + (bc ^ ((r & 7) << 4)));
      }
#pragma unroll
      for (int m = 0; m < 4; ++m)
#pragma unroll
        for (int n = 0; n < 4; ++n)
          acc[m][n] = __builtin_amdgcn_mfma_f32_16x16x32_bf16(a[m], b[n], acc[m][n], 0, 0, 0);
    }
  }
#pragma unroll
  for (int n = 0; n < 4; ++n) {
    int gcol = n0 + wn * 64 + n * 16 + (lane & 15);
    float bias = b2[e * On + gcol];
#pragma unroll
    for (int m = 0; m < 4; ++m) {
      int grow = m0 + wm * 64 + m * 16 + ((lane >> 4) << 2);
#pragma unroll
      for (int r = 0; r < 4; ++r)
        y[(size_t)(grow + r) * On + gcol] = f2bf(acc[m][n][r] + bias);
    }
  }
}

// ---------------- combine: out[t] = w0*y[p0] + w1*y[p1] ----------------
__global__ __launch_bounds__(256) void k_combine(const unsigned short* __restrict__ y,
    const int* __restrict__ pos_tk, const float* __restrict__ top_w,
    float* __restrict__ out) {
  int wid = threadIdx.x >> 6, lane = threadIdx.x & 63;
  int t = blockIdx.x * 4 + wid;
  int p0 = pos_tk[t * 2], p1 = pos_tk[t * 2 + 1];
  float w0 = top_w[t * 2], w1 = top_w[t * 2 + 1];
  bf16x8 a = *(const bf16x8*)(y + (size_t)p0 * On + lane * 8);
  bf16x8 b = *(const bf16x8*)(y + (size_t)p1 * On + lane * 8);
  f32x4 o0, o1;
#pragma unroll
  for (int j = 0; j < 4; ++j) {
    o0[j] = w0 * bf2f(a[j]) + w1 * bf2f(b[j]);
    o1[j] = w0 * bf2f(a[j + 4]) + w1 * bf2f(b[j + 4]);
  }
  float* op = out + (size_t)t * On + lane * 8;
  *(f32x4*)op = o0;
  *(f32x4*)(op + 4) = o1;
}

extern "C" void kernel_launch(void* const* d_in, const int* in_sizes, int n_in,
                              void* d_out, int out_size, void* d_ws, size_t ws_size,
                              hipStream_t stream) {
  const float* x  = (const float*)d_in[0];
  const float* gw = (const float*)d_in[1];
  const float* gb = (const float*)d_in[2];
  const float* w1 = (const float*)d_in[3];
  const float* b1 = (const float*)d_in[4];
  const float* w2 = (const float*)d_in[5];
  const float* b2 = (const float*)d_in[6];
  float* out     = (float*)d_out;
  float* raw_out = out + (size_t)Bn * On;
  float* idx_out = raw_out + (size_t)Bn * En;
  float* ent_out = idx_out + (size_t)Bn * 2;

  char* ws = (char*)d_ws;
  size_t off = 0;
  auto alloc = [&](size_t bytes) { char* p = ws + off; off += (bytes + 255) & ~(size_t)255; return p; };
  unsigned short* xb   = (unsigned short*)alloc((size_t)Bn * Dn * 2);
  unsigned short* w1t  = (unsigned short*)alloc((size_t)En * Hn * Dn * 2);
  unsigned short* w2t  = (unsigned short*)alloc((size_t)En * On * Hn * 2);
  unsigned short* hbuf = (unsigned short*)alloc((size_t)MAXP * Hn * 2);
  unsigned short* ybuf = (unsigned short*)alloc((size_t)MAXP * On * 2);
  int*   tok    = (int*)alloc((size_t)MAXP * 4);
  int*   pos_tk = (int*)alloc((size_t)NPAIR * 4);
  int*   top_e  = (int*)alloc((size_t)NPAIR * 4);
  float* top_w  = (float*)alloc((size_t)NPAIR * 4);
  int*   bc     = (int*)alloc(SBLK * 8 * 4);
  int*   ob     = (int*)alloc(SBLK * 8 * 4);
  int*   tile_expert = (int*)alloc(MTILES * 4);
  float* entp   = (float*)alloc(4096 * 4);

  // padding rows of tok -> token 0 (harmless: padded h/y rows are never read)
  hipMemsetAsync(tok, 0, (size_t)MAXP * 4, stream);

  k_prep<<<12288, 256, 0, stream>>>(x, gw, gb, w1, w2, xb, w1t, w2t,
                                    raw_out, idx_out, top_e, top_w, entp);
  k_hist<<<SBLK, 512, 0, stream>>>(top_e, bc);
  k_offsets<<<1, 512, 0, stream>>>(bc, ob, tile_expert, entp, ent_out);
  k_scatter2<<<SBLK, 512, 0, stream>>>(top_e, top_w, ob, tok, pos_tk);
  k_gemm1<<<MTILES * (Hn / 128), 256, 0, stream>>>(xb, w1t, b1, tok, tile_expert, hbuf);
  k_gemm2<<<MTILES * (On / 128), 256, 0, stream>>>(hbuf, w2t, b2, tile_expert, ybuf);
  k_combine<<<Bn / 4, 256, 0, stream>>>(ybuf, pos_tk, top_w, out);
}